// Round 1
// 1080.353 us; speedup vs baseline: 1.1546x; 1.1546x over previous
//
#include <hip/hip_runtime.h>
#include <hip/hip_bf16.h>

typedef short short8_t __attribute__((ext_vector_type(8)));
typedef float float4_t __attribute__((ext_vector_type(4)));

#define MFMA16(A, B, C) __builtin_amdgcn_mfma_f32_16x16x32_bf16((A), (B), (C), 0, 0, 0)

#define SEQ 2048
#define HD 128
#define NH 32
#define NKV 8

__device__ inline short f2bs(float f) {
    union { __hip_bfloat16 h; short s; } u;
    u.h = __float2bfloat16(f);
    return u.s;
}

__device__ inline short8_t load8(const __hip_bfloat16* p) {
    return *(const short8_t*)p;
}
__device__ inline short8_t load8(const float* p) {
    float4_t a = *(const float4_t*)p;
    float4_t b = *(const float4_t*)(p + 4);
    short8_t r;
    r[0] = f2bs(a[0]); r[1] = f2bs(a[1]); r[2] = f2bs(a[2]); r[3] = f2bs(a[3]);
    r[4] = f2bs(b[0]); r[5] = f2bs(b[1]); r[6] = f2bs(b[2]); r[7] = f2bs(b[3]);
    return r;
}

__device__ inline void store_c(__hip_bfloat16* p, float v) { *p = __float2bfloat16(v); }
__device__ inline void store_c(float* p, float v)          { *p = v; }

// async global->LDS DMA, 16B per lane. LDS dest must be WAVE-UNIFORM base;
// hardware adds lane*16 (guide §5 caveat, m104/m108).
__device__ __forceinline__ void gld_lds16(const __hip_bfloat16* g, __hip_bfloat16* l) {
    __builtin_amdgcn_global_load_lds(
        (const __attribute__((address_space(1))) unsigned int*)g,
        (__attribute__((address_space(3))) unsigned int*)l,
        16, 0, 0);
}

// ---------------------------------------------------------------------------
// fp32 -> bf16 conversion pass (memory-bound, float4 loads, 16B/lane).
// ---------------------------------------------------------------------------
__global__ __launch_bounds__(256) void cvt_bf16(
    const float* __restrict__ in, __hip_bfloat16* __restrict__ out, int n8)
{
    int stride = gridDim.x * 256;
    for (int i = blockIdx.x * 256 + threadIdx.x; i < n8; i += stride) {
        short8_t r = load8(in + (size_t)i * 8);
        *(short8_t*)(out + (size_t)i * 8) = r;
    }
}

// ---------------------------------------------------------------------------
// C[m][n] = sum_k A[m][k] * B[n][k]  (bf16 operands, row-major K-contiguous).
// m97 structure: 128x128 tile, BK=32, linear LDS, global_load_lds width=16,
// 2 barriers per K-step. If TRC: store transposed per-batch for V^T.
// ---------------------------------------------------------------------------
template <typename TC, bool TRC = false>
__global__ __launch_bounds__(256) void gemm_bt(
    const __hip_bfloat16* __restrict__ A,
    const __hip_bfloat16* __restrict__ B,
    TC* __restrict__ C,
    int M, int N, int K)
{
    // linear layout [128][32] bf16 = 8KB each (NO pad: global_load_lds writes
    // base + lane*16 contiguously)
    __shared__ __hip_bfloat16 As[128 * 32];
    __shared__ __hip_bfloat16 Bs[128 * 32];

    const int tid  = threadIdx.x;
    const int wave = tid >> 6;
    const int lane = tid & 63;
    const int quad = lane >> 4;
    const int l16  = lane & 15;
    const int m0 = blockIdx.y * 128;
    const int n0 = blockIdx.x * 128;
    const int wm = (wave >> 1) * 64;
    const int wn = (wave & 1) * 64;

    // staging: chunk c = i*256 + tid covers LDS bytes [c*16, c*16+16)
    //  <- global row (c>>2), cols [(c&3)*8, +8)   (row-major [128][32])
    const int row0 = tid >> 2;
    const int col0 = (tid & 3) * 8;

    const __hip_bfloat16* Abase = A + (size_t)m0 * K;
    const __hip_bfloat16* Bbase = B + (size_t)n0 * K;
    // wave-uniform LDS bases: call i, wave w -> chunk base i*256 + w*64
    __hip_bfloat16* AsW = As + wave * 512;
    __hip_bfloat16* BsW = Bs + wave * 512;

    float4_t acc[4][4] = {};

    for (int k0 = 0; k0 < K; k0 += 32) {
        __syncthreads();   // prev tile's ds_reads done before DMA overwrites
        gld_lds16(Abase + (size_t)row0        * K + k0 + col0, AsW);
        gld_lds16(Abase + (size_t)(row0 + 64) * K + k0 + col0, AsW + 2048);
        gld_lds16(Bbase + (size_t)row0        * K + k0 + col0, BsW);
        gld_lds16(Bbase + (size_t)(row0 + 64) * K + k0 + col0, BsW + 2048);
        __syncthreads();   // compiler emits vmcnt(0) drain -> tile landed

        short8_t af[4], bf[4];
#pragma unroll
        for (int t = 0; t < 4; t++)
            af[t] = *(const short8_t*)&As[(wm + t * 16 + l16) * 32 + quad * 8];
#pragma unroll
        for (int t = 0; t < 4; t++)
            bf[t] = *(const short8_t*)&Bs[(wn + t * 16 + l16) * 32 + quad * 8];
#pragma unroll
        for (int mt = 0; mt < 4; mt++)
#pragma unroll
            for (int nt = 0; nt < 4; nt++)
                acc[mt][nt] = MFMA16(af[mt], bf[nt], acc[mt][nt]);
    }

#pragma unroll
    for (int mt = 0; mt < 4; mt++)
#pragma unroll
        for (int nt = 0; nt < 4; nt++)
#pragma unroll
            for (int r = 0; r < 4; r++) {
                int row = m0 + wm + mt * 16 + quad * 4 + r;
                int col = n0 + wn + nt * 16 + l16;
                if constexpr (TRC) {
                    int bb = row >> 11, ss = row & (SEQ - 1);
                    C[((size_t)bb * N + col) * SEQ + ss] = __float2bfloat16(acc[mt][nt][r]);
                } else {
                    store_c(&C[(size_t)row * N + col], acc[mt][nt][r]);
                }
            }
}

// ---------------------------------------------------------------------------
// RoPE in-place; freqs fp32 [SEQ][64].
// ---------------------------------------------------------------------------
__global__ __launch_bounds__(256) void rope_kernel(
    __hip_bfloat16* __restrict__ x,
    const float* __restrict__ cs,
    const float* __restrict__ sn,
    int npairs, int shift)
{
    int pi = blockIdx.x * 256 + threadIdx.x;
    if (pi >= npairs) return;
    int cols = 1 << shift;
    int cp   = pi & (cols - 1);
    int row  = pi >> shift;
    int d    = cp & 63;
    int pos  = row & (SEQ - 1);
    float c = cs[pos * 64 + d];
    float s = sn[pos * 64 + d];
    __hip_bfloat16* p = x + (((size_t)row) << (shift + 1)) + (size_t)cp * 2;
    float x0 = __bfloat162float(p[0]);
    float x1 = __bfloat162float(p[1]);
    p[0] = __float2bfloat16(x0 * c - x1 * s);
    p[1] = __float2bfloat16(x0 * s + x1 * c);
}

// ---------------------------------------------------------------------------
// Causal GQA flash attention, swapped-operand layout.
// Grid: (S/64, NH, B), block 256 = 4 waves; wave w owns q rows w*16..+15.
// ---------------------------------------------------------------------------
__global__ __launch_bounds__(256) void flash_kernel(
    const __hip_bfloat16* __restrict__ Q,
    const __hip_bfloat16* __restrict__ Km,
    const __hip_bfloat16* __restrict__ VT,
    __hip_bfloat16* __restrict__ O)
{
    __shared__ __hip_bfloat16 Ks[64][136];   // 272B row = 17 superbanks (good)
    __shared__ __hip_bfloat16 Vt[128][72];   // V^T tile: [d][key]

    const int tid  = threadIdx.x;
    const int wave = tid >> 6;
    const int lane = tid & 63;
    const int quad = lane >> 4;
    const int l16  = lane & 15;
    const int qt = (int)gridDim.x - 1 - (int)blockIdx.x;  // heavy blocks first
    const int h  = blockIdx.y;
    const int b  = blockIdx.z;
    const int kvh = h >> 2;
    const int q0  = qt * 64;
    const float scale = 0.08838834764831845f;  // 1/sqrt(128)
    const int qrow = q0 + wave * 16 + l16;     // this lane's q row

    // Q B-fragments straight from global (16 rows x 64B contiguous per load)
    short8_t qf[4];
    {
        const __hip_bfloat16* qp = Q + (size_t)(b * SEQ + qrow) * (NH * HD) + h * HD + quad * 8;
#pragma unroll
        for (int kk = 0; kk < 4; kk++)
            qf[kk] = *(const short8_t*)(qp + kk * 32);
    }

    float4_t acc[8] = {};          // O^T: acc[dm], d = dm*16 + quad*4 + r, q = l16
    float m_st = -1e30f, l_st = 0.f;

    const __hip_bfloat16* vbase = VT + ((size_t)(b * NKV + kvh) * HD) * SEQ;

    for (int kt = 0; kt <= qt; kt++) {
        __syncthreads();
        {
            const int seg = (tid & 15) * 8;
            const int row = tid >> 4;
#pragma unroll
            for (int i = 0; i < 4; i++) {
                int r = row + i * 16;
                *(uint4*)&Ks[r][seg] =
                    *(const uint4*)(Km + (size_t)(b * SEQ + kt * 64 + r) * (NKV * HD) + kvh * HD + seg);
            }
#pragma unroll
            for (int t = 0; t < 4; t++) {
                int c = tid + t * 256;
                int d = c >> 3, sl = (c & 7) * 8;
                *(uint4*)&Vt[d][sl] = *(const uint4*)(vbase + (size_t)d * SEQ + kt * 64 + sl);
            }
        }
        __syncthreads();

        // S^T[key][q]
        float4_t st[4] = {};
#pragma unroll
        for (int kk = 0; kk < 4; kk++)
#pragma unroll
            for (int mt = 0; mt < 4; mt++) {
                short8_t kf = *(const short8_t*)&Ks[mt * 16 + l16][kk * 32 + quad * 8];
                st[mt] = MFMA16(kf, qf[kk], st[mt]);
            }

        // per-lane softmax over this lane's 16 keys, then reduce across quads
        float mx = -1e30f;
#pragma unroll
        for (int mt = 0; mt < 4; mt++)
#pragma unroll
            for (int r = 0; r < 4; r++) {
                int key = kt * 64 + mt * 16 + quad * 4 + r;
                float s = st[mt][r] * scale;
                if (key > qrow) s = -1e30f;
                st[mt][r] = s;
                mx = fmaxf(mx, s);
            }
        mx = fmaxf(mx, __shfl_xor(mx, 16, 64));
        mx = fmaxf(mx, __shfl_xor(mx, 32, 64));
        float mnew  = fmaxf(m_st, mx);
        float alpha = __expf(m_st - mnew);
        float p[4][4];
        float rsum = 0.f;
#pragma unroll
        for (int mt = 0; mt < 4; mt++)
#pragma unroll
            for (int r = 0; r < 4; r++) {
                float pv = __expf(st[mt][r] - mnew);
                p[mt][r] = pv;
                rsum += pv;
            }
        rsum += __shfl_xor(rsum, 16, 64);
        rsum += __shfl_xor(rsum, 32, 64);
        l_st = l_st * alpha + rsum;
        m_st = mnew;
#pragma unroll
        for (int dm = 0; dm < 8; dm++)
            acc[dm] *= alpha;

        // pack P pairs: pk[mt][h] = keys (kt*64 + mt*16 + quad*4 + 2h, +2h+1)
        uint32_t pk[4][2];
#pragma unroll
        for (int mt = 0; mt < 4; mt++)
#pragma unroll
            for (int hh = 0; hh < 2; hh++)
                pk[mt][hh] = (uint32_t)(unsigned short)f2bs(p[mt][2 * hh]) |
                             ((uint32_t)(unsigned short)f2bs(p[mt][2 * hh + 1]) << 16);

        // build P^T B-fragments via cross-lane permutes
        const int src0 = ((quad & 1) * 2) * 16 + l16;
        const int src1 = src0 + 16;
        const bool hi_mt = (quad >> 1) != 0;
#pragma unroll
        for (int kk2 = 0; kk2 < 2; kk2++) {
            uint32_t a0 = (uint32_t)__shfl((int)pk[kk2 * 2][0],     src0, 64);
            uint32_t a1 = (uint32_t)__shfl((int)pk[kk2 * 2][1],     src0, 64);
            uint32_t a2 = (uint32_t)__shfl((int)pk[kk2 * 2][0],     src1, 64);
            uint32_t a3 = (uint32_t)__shfl((int)pk[kk2 * 2][1],     src1, 64);
            uint32_t b0 = (uint32_t)__shfl((int)pk[kk2 * 2 + 1][0], src0, 64);
            uint32_t b1 = (uint32_t)__shfl((int)pk[kk2 * 2 + 1][1], src0, 64);
            uint32_t b2 = (uint32_t)__shfl((int)pk[kk2 * 2 + 1][0], src1, 64);
            uint32_t b3 = (uint32_t)__shfl((int)pk[kk2 * 2 + 1][1], src1, 64);
            union { uint32_t u[4]; short8_t v; } pf;
            pf.u[0] = hi_mt ? b0 : a0;
            pf.u[1] = hi_mt ? b1 : a1;
            pf.u[2] = hi_mt ? b2 : a2;
            pf.u[3] = hi_mt ? b3 : a3;
#pragma unroll
            for (int dm = 0; dm < 8; dm++) {
                short8_t vf = *(const short8_t*)&Vt[dm * 16 + l16][kk2 * 32 + quad * 8];
                acc[dm] = MFMA16(vf, pf.v, acc[dm]);
            }
        }
    }

    // epilogue: O^T -> O via LDS transpose (reuse Ks; stride 136)
    __syncthreads();   // all waves done reading Ks/Vt
    __hip_bfloat16* Ot = &Ks[0][0];
    float inv_l = 1.f / l_st;
#pragma unroll
    for (int dm = 0; dm < 8; dm++)
#pragma unroll
        for (int hh = 0; hh < 2; hh++) {
            uint32_t pv = (uint32_t)(unsigned short)f2bs(acc[dm][2 * hh] * inv_l) |
                          ((uint32_t)(unsigned short)f2bs(acc[dm][2 * hh + 1] * inv_l) << 16);
            *(uint32_t*)&Ot[(size_t)(wave * 16 + l16) * 136 + dm * 16 + quad * 4 + 2 * hh] = pv;
        }
    __syncthreads();
#pragma unroll
    for (int i = 0; i < 4; i++) {
        int c  = i * 64 + lane;
        int r2 = c >> 4, ch = c & 15;
        uint4 v = *(const uint4*)&Ot[(size_t)(wave * 16 + r2) * 136 + ch * 8];
        *(uint4*)(O + (size_t)(b * SEQ + q0 + wave * 16 + r2) * (NH * HD) + h * HD + ch * 8) = v;
    }
}

// ---------------------------------------------------------------------------
extern "C" void kernel_launch(void* const* d_in, const int* in_sizes, int n_in,
                              void* d_out, int out_size, void* d_ws, size_t ws_size,
                              hipStream_t stream)
{
    const float* x  = (const float*)d_in[0];
    const float* fc = (const float*)d_in[1];
    const float* fs = (const float*)d_in[2];
    const float* wq = (const float*)d_in[3];
    const float* wk = (const float*)d_in[4];
    const float* wv = (const float*)d_in[5];
    const float* wo = (const float*)d_in[6];
    float* out = (float*)d_out;

    const int BS = 2 * SEQ;  // 4096 rows
    char* ws = (char*)d_ws;
    // workspace layout (112 MB):
    //   [0,32M)    q     4096x4096 bf16
    //   [32,40M)   k     4096x1024 bf16
    //   [40,48M)   vT    [b][kvh][d][2048] bf16
    //   [48,80M)   xb (x in bf16)  -- aliased with attn (xb dead before flash)
    //   [80,112M)  wb    shared converted-weight slot (wq/wk/wv/wo in turn)
    __hip_bfloat16* q    = (__hip_bfloat16*)(ws);
    __hip_bfloat16* k    = (__hip_bfloat16*)(ws + 33554432ull);
    __hip_bfloat16* vT   = (__hip_bfloat16*)(ws + 41943040ull);
    __hip_bfloat16* xb   = (__hip_bfloat16*)(ws + 50331648ull);
    __hip_bfloat16* attn = xb;  // alias: xb dead once projections are done
    __hip_bfloat16* wb   = (__hip_bfloat16*)(ws + 83886080ull);

    cvt_bf16<<<2048, 256, 0, stream>>>(x,  xb, (BS * 4096) / 8);
    cvt_bf16<<<2048, 256, 0, stream>>>(wq, wb, (4096 * 4096) / 8);
    gemm_bt<__hip_bfloat16, false><<<dim3(32, 32), 256, 0, stream>>>(xb, wb, q,  BS, NH * HD,  4096);
    cvt_bf16<<<2048, 256, 0, stream>>>(wk, wb, (1024 * 4096) / 8);
    gemm_bt<__hip_bfloat16, false><<<dim3(8, 32),  256, 0, stream>>>(xb, wb, k,  BS, NKV * HD, 4096);
    cvt_bf16<<<2048, 256, 0, stream>>>(wv, wb, (1024 * 4096) / 8);
    gemm_bt<__hip_bfloat16, true ><<<dim3(8, 32),  256, 0, stream>>>(xb, wb, vT, BS, NKV * HD, 4096);

    {
        int npq = BS * NH * 64;
        rope_kernel<<<(npq + 255) / 256, 256, 0, stream>>>(q, fc, fs, npq, 11);
        int npk = BS * NKV * 64;
        rope_kernel<<<(npk + 255) / 256, 256, 0, stream>>>(k, fc, fs, npk, 9);
    }

    flash_kernel<<<dim3(SEQ / 64, NH, 2), 256, 0, stream>>>(q, k, vT, attn);

    cvt_bf16<<<2048, 256, 0, stream>>>(wo, wb, (4096 * 4096) / 8);
    gemm_bt<float, false><<<dim3(32, 32), 256, 0, stream>>>(attn, wb, out, BS, NH * HD, 4096);
}

// Round 2
// 1023.701 us; speedup vs baseline: 1.2185x; 1.0553x over previous
//
#include <hip/hip_runtime.h>
#include <hip/hip_bf16.h>

typedef short short8_t __attribute__((ext_vector_type(8)));
typedef float float4_t __attribute__((ext_vector_type(4)));

#define MFMA16(A, B, C) __builtin_amdgcn_mfma_f32_16x16x32_bf16((A), (B), (C), 0, 0, 0)

#define SEQ 2048
#define HD 128
#define NH 32
#define NKV 8

__device__ inline short f2bs(float f) {
    union { __hip_bfloat16 h; short s; } u;
    u.h = __float2bfloat16(f);
    return u.s;
}

__device__ inline short8_t load8(const __hip_bfloat16* p) {
    return *(const short8_t*)p;
}
__device__ inline short8_t load8(const float* p) {
    float4_t a = *(const float4_t*)p;
    float4_t b = *(const float4_t*)(p + 4);
    short8_t r;
    r[0] = f2bs(a[0]); r[1] = f2bs(a[1]); r[2] = f2bs(a[2]); r[3] = f2bs(a[3]);
    r[4] = f2bs(b[0]); r[5] = f2bs(b[1]); r[6] = f2bs(b[2]); r[7] = f2bs(b[3]);
    return r;
}

__device__ inline void store_c(__hip_bfloat16* p, float v) { *p = __float2bfloat16(v); }
__device__ inline void store_c(float* p, float v)          { *p = v; }

// async global->LDS DMA, 16B per lane. LDS dest must be WAVE-UNIFORM base;
// hardware adds lane*16 (guide §5 caveat, m104/m108).
__device__ __forceinline__ void gld_lds16(const __hip_bfloat16* g, __hip_bfloat16* l) {
    __builtin_amdgcn_global_load_lds(
        (const __attribute__((address_space(1))) unsigned int*)g,
        (__attribute__((address_space(3))) unsigned int*)l,
        16, 0, 0);
}

// ---------------------------------------------------------------------------
// fp32 -> bf16 conversion pass (memory-bound, float4 loads, 16B/lane).
// ---------------------------------------------------------------------------
__global__ __launch_bounds__(256) void cvt_bf16(
    const float* __restrict__ in, __hip_bfloat16* __restrict__ out, int n8)
{
    int stride = gridDim.x * 256;
    for (int i = blockIdx.x * 256 + threadIdx.x; i < n8; i += stride) {
        short8_t r = load8(in + (size_t)i * 8);
        *(short8_t*)(out + (size_t)i * 8) = r;
    }
}

// ---------------------------------------------------------------------------
// C[m][n] = sum_k A[m][k] * B[n][k]  (bf16 operands, row-major K-contiguous).
// m97 structure: 128x128 tile, BK=32, linear LDS, global_load_lds width=16,
// 2 barriers per K-step. If TRC: store transposed per-batch for V^T.
// ---------------------------------------------------------------------------
template <typename TC, bool TRC = false>
__global__ __launch_bounds__(256) void gemm_bt(
    const __hip_bfloat16* __restrict__ A,
    const __hip_bfloat16* __restrict__ B,
    TC* __restrict__ C,
    int M, int N, int K)
{
    __shared__ __hip_bfloat16 As[128 * 32];
    __shared__ __hip_bfloat16 Bs[128 * 32];

    const int tid  = threadIdx.x;
    const int wave = tid >> 6;
    const int lane = tid & 63;
    const int quad = lane >> 4;
    const int l16  = lane & 15;
    const int m0 = blockIdx.y * 128;
    const int n0 = blockIdx.x * 128;
    const int wm = (wave >> 1) * 64;
    const int wn = (wave & 1) * 64;

    const int row0 = tid >> 2;
    const int col0 = (tid & 3) * 8;

    const __hip_bfloat16* Abase = A + (size_t)m0 * K;
    const __hip_bfloat16* Bbase = B + (size_t)n0 * K;
    __hip_bfloat16* AsW = As + wave * 512;
    __hip_bfloat16* BsW = Bs + wave * 512;

    float4_t acc[4][4] = {};

    for (int k0 = 0; k0 < K; k0 += 32) {
        __syncthreads();
        gld_lds16(Abase + (size_t)row0        * K + k0 + col0, AsW);
        gld_lds16(Abase + (size_t)(row0 + 64) * K + k0 + col0, AsW + 2048);
        gld_lds16(Bbase + (size_t)row0        * K + k0 + col0, BsW);
        gld_lds16(Bbase + (size_t)(row0 + 64) * K + k0 + col0, BsW + 2048);
        __syncthreads();

        short8_t af[4], bf[4];
#pragma unroll
        for (int t = 0; t < 4; t++)
            af[t] = *(const short8_t*)&As[(wm + t * 16 + l16) * 32 + quad * 8];
#pragma unroll
        for (int t = 0; t < 4; t++)
            bf[t] = *(const short8_t*)&Bs[(wn + t * 16 + l16) * 32 + quad * 8];
#pragma unroll
        for (int mt = 0; mt < 4; mt++)
#pragma unroll
            for (int nt = 0; nt < 4; nt++)
                acc[mt][nt] = MFMA16(af[mt], bf[nt], acc[mt][nt]);
    }

#pragma unroll
    for (int mt = 0; mt < 4; mt++)
#pragma unroll
        for (int nt = 0; nt < 4; nt++)
#pragma unroll
            for (int r = 0; r < 4; r++) {
                int row = m0 + wm + mt * 16 + quad * 4 + r;
                int col = n0 + wn + nt * 16 + l16;
                if constexpr (TRC) {
                    int bb = row >> 11, ss = row & (SEQ - 1);
                    C[((size_t)bb * N + col) * SEQ + ss] = __float2bfloat16(acc[mt][nt][r]);
                } else {
                    store_c(&C[(size_t)row * N + col], acc[mt][nt][r]);
                }
            }
}

// ---------------------------------------------------------------------------
// RoPE in-place; freqs fp32 [SEQ][64].
// ---------------------------------------------------------------------------
__global__ __launch_bounds__(256) void rope_kernel(
    __hip_bfloat16* __restrict__ x,
    const float* __restrict__ cs,
    const float* __restrict__ sn,
    int npairs, int shift)
{
    int pi = blockIdx.x * 256 + threadIdx.x;
    if (pi >= npairs) return;
    int cols = 1 << shift;
    int cp   = pi & (cols - 1);
    int row  = pi >> shift;
    int d    = cp & 63;
    int pos  = row & (SEQ - 1);
    float c = cs[pos * 64 + d];
    float s = sn[pos * 64 + d];
    __hip_bfloat16* p = x + (((size_t)row) << (shift + 1)) + (size_t)cp * 2;
    float x0 = __bfloat162float(p[0]);
    float x1 = __bfloat162float(p[1]);
    p[0] = __float2bfloat16(x0 * c - x1 * s);
    p[1] = __float2bfloat16(x0 * s + x1 * c);
}

// ---------------------------------------------------------------------------
// Causal GQA flash attention, swapped-operand layout.
// Grid: (S/64, NH/2, B), block 512 = 8 waves covering TWO heads that share
// one kvh (h = 2*by + (wave>>2)); one K/V stage feeds 128 q-rows of MFMA.
// Per wave: 16 q rows. Async-stage split: next tile's global loads issue
// before compute, LDS writes after the post-compute barrier (T14).
// Mask only on the diagonal tile; defer-max rescale (T13, THR=8).
// ---------------------------------------------------------------------------
__global__ __launch_bounds__(512, 4) void flash_kernel(
    const __hip_bfloat16* __restrict__ Q,
    const __hip_bfloat16* __restrict__ Km,
    const __hip_bfloat16* __restrict__ VT,
    __hip_bfloat16* __restrict__ O)
{
    // Ks[64][136] | Vt[128][72]  (35840 B); epilogue reuses whole buffer as
    // Ot[128][136] (34816 B).
    __shared__ __hip_bfloat16 smem[64 * 136 + 128 * 72];
    __hip_bfloat16* Ks = smem;
    __hip_bfloat16* Vt = smem + 64 * 136;

    const int tid  = threadIdx.x;
    const int wave = tid >> 6;
    const int lane = tid & 63;
    const int quad = lane >> 4;
    const int l16  = lane & 15;
    const int qt = (int)gridDim.x - 1 - (int)blockIdx.x;  // heavy blocks first
    const int h  = (int)blockIdx.y * 2 + (wave >> 2);
    const int b  = blockIdx.z;
    const int kvh = blockIdx.y >> 1;                      // same for both heads
    const int q0  = qt * 64;
    const float scale = 0.08838834764831845f;  // 1/sqrt(128)
    const int qrow = q0 + (wave & 3) * 16 + l16;          // this lane's q row

    // Q B-fragments straight from global
    short8_t qf[4];
    {
        const __hip_bfloat16* qp = Q + (size_t)(b * SEQ + qrow) * (NH * HD) + h * HD + quad * 8;
#pragma unroll
        for (int kk = 0; kk < 4; kk++)
            qf[kk] = *(const short8_t*)(qp + kk * 32);
    }

    float4_t acc[8] = {};          // O^T: acc[dm], d = dm*16 + quad*4 + r, q = l16
    float m_st = -1e30f, l_st = 0.f;

    const __hip_bfloat16* vbase = VT + ((size_t)(b * NKV + kvh) * HD) * SEQ;
    const __hip_bfloat16* kbase = Km + (size_t)(b * SEQ) * (NKV * HD) + kvh * HD;

    // staging indices (512 threads: K tile 64x128 = 2 uint4/thread, V same)
    const int krow0 = tid >> 4;          // 0..31
    const int kseg  = (tid & 15) * 8;
    const int vd0   = tid >> 3;          // 0..63
    const int vsl   = (tid & 7) * 8;

    uint4 kr0, kr1, vr0, vr1;
#define STAGE_LOAD(KT)                                                              \
    {                                                                               \
        kr0 = *(const uint4*)(kbase + (size_t)((KT) * 64 + krow0)      * (NKV * HD) + kseg); \
        kr1 = *(const uint4*)(kbase + (size_t)((KT) * 64 + krow0 + 32) * (NKV * HD) + kseg); \
        vr0 = *(const uint4*)(vbase + (size_t)vd0        * SEQ + (KT) * 64 + vsl);  \
        vr1 = *(const uint4*)(vbase + (size_t)(vd0 + 64) * SEQ + (KT) * 64 + vsl);  \
    }
#define STAGE_WRITE()                                         \
    {                                                         \
        *(uint4*)&Ks[(size_t)krow0        * 136 + kseg] = kr0; \
        *(uint4*)&Ks[(size_t)(krow0 + 32) * 136 + kseg] = kr1; \
        *(uint4*)&Vt[(size_t)vd0          * 72  + vsl]  = vr0; \
        *(uint4*)&Vt[(size_t)(vd0 + 64)   * 72  + vsl]  = vr1; \
    }

    STAGE_LOAD(0);
    STAGE_WRITE();
    __syncthreads();

    for (int kt = 0; kt <= qt; kt++) {
        const bool last = (kt == qt);
        if (!last) STAGE_LOAD(kt + 1);   // issue early; lands under compute

        // S^T[key][q]
        float4_t st[4] = {};
#pragma unroll
        for (int kk = 0; kk < 4; kk++)
#pragma unroll
            for (int mt = 0; mt < 4; mt++) {
                short8_t kf = *(const short8_t*)&Ks[(size_t)(mt * 16 + l16) * 136 + kk * 32 + quad * 8];
                st[mt] = MFMA16(kf, qf[kk], st[mt]);
            }

        // softmax over this lane's 16 keys; mask only on the diagonal tile
        float mx = -1e30f;
        if (last) {
#pragma unroll
            for (int mt = 0; mt < 4; mt++)
#pragma unroll
                for (int r = 0; r < 4; r++) {
                    int key = kt * 64 + mt * 16 + quad * 4 + r;
                    float s = st[mt][r] * scale;
                    if (key > qrow) s = -1e30f;
                    st[mt][r] = s;
                    mx = fmaxf(mx, s);
                }
        } else {
#pragma unroll
            for (int mt = 0; mt < 4; mt++)
#pragma unroll
                for (int r = 0; r < 4; r++) {
                    float s = st[mt][r] * scale;
                    st[mt][r] = s;
                    mx = fmaxf(mx, s);
                }
        }
        mx = fmaxf(mx, __shfl_xor(mx, 16, 64));
        mx = fmaxf(mx, __shfl_xor(mx, 32, 64));

        // defer-max: skip rescale while growth bounded (P <= e^8, f32-safe)
        float mcur;
        if (__all(mx <= m_st + 8.f)) {
            mcur = m_st;
        } else {
            float mnew  = fmaxf(m_st, mx);
            float alpha = __expf(m_st - mnew);
            l_st *= alpha;
#pragma unroll
            for (int dm = 0; dm < 8; dm++)
                acc[dm] *= alpha;
            m_st = mnew;
            mcur = mnew;
        }

        // exp + pack directly into bf16 pairs (keys mt*16 + quad*4 + {2h,2h+1})
        uint32_t pk[4][2];
        float rsum = 0.f;
#pragma unroll
        for (int mt = 0; mt < 4; mt++)
#pragma unroll
            for (int hh = 0; hh < 2; hh++) {
                float p0 = __expf(st[mt][2 * hh]     - mcur);
                float p1 = __expf(st[mt][2 * hh + 1] - mcur);
                rsum += p0 + p1;
                pk[mt][hh] = (uint32_t)(unsigned short)f2bs(p0) |
                             ((uint32_t)(unsigned short)f2bs(p1) << 16);
            }
        rsum += __shfl_xor(rsum, 16, 64);
        rsum += __shfl_xor(rsum, 32, 64);
        l_st += rsum;

        // build P^T B-fragments via cross-lane permutes
        const int src0 = ((quad & 1) * 2) * 16 + l16;
        const int src1 = src0 + 16;
        const bool hi_mt = (quad >> 1) != 0;
#pragma unroll
        for (int kk2 = 0; kk2 < 2; kk2++) {
            uint32_t a0 = (uint32_t)__shfl((int)pk[kk2 * 2][0],     src0, 64);
            uint32_t a1 = (uint32_t)__shfl((int)pk[kk2 * 2][1],     src0, 64);
            uint32_t a2 = (uint32_t)__shfl((int)pk[kk2 * 2][0],     src1, 64);
            uint32_t a3 = (uint32_t)__shfl((int)pk[kk2 * 2][1],     src1, 64);
            uint32_t b0 = (uint32_t)__shfl((int)pk[kk2 * 2 + 1][0], src0, 64);
            uint32_t b1 = (uint32_t)__shfl((int)pk[kk2 * 2 + 1][1], src0, 64);
            uint32_t b2 = (uint32_t)__shfl((int)pk[kk2 * 2 + 1][0], src1, 64);
            uint32_t b3 = (uint32_t)__shfl((int)pk[kk2 * 2 + 1][1], src1, 64);
            union { uint32_t u[4]; short8_t v; } pf;
            pf.u[0] = hi_mt ? b0 : a0;
            pf.u[1] = hi_mt ? b1 : a1;
            pf.u[2] = hi_mt ? b2 : a2;
            pf.u[3] = hi_mt ? b3 : a3;
#pragma unroll
            for (int dm = 0; dm < 8; dm++) {
                short8_t vf = *(const short8_t*)&Vt[(size_t)(dm * 16 + l16) * 72 + kk2 * 32 + quad * 8];
                acc[dm] = MFMA16(vf, pf.v, acc[dm]);
            }
        }

        __syncthreads();               // all waves done reading tile kt
        if (!last) {
            STAGE_WRITE();             // waits vmcnt internally (reg use)
            __syncthreads();           // tile kt+1 visible
        }
    }

    // epilogue: O^T -> O via LDS transpose; reuse smem as Ot[128][136]
    __hip_bfloat16* Ot = smem;
    float inv_l = 1.f / l_st;
#pragma unroll
    for (int dm = 0; dm < 8; dm++)
#pragma unroll
        for (int hh = 0; hh < 2; hh++) {
            uint32_t pv = (uint32_t)(unsigned short)f2bs(acc[dm][2 * hh] * inv_l) |
                          ((uint32_t)(unsigned short)f2bs(acc[dm][2 * hh + 1] * inv_l) << 16);
            *(uint32_t*)&Ot[(size_t)(wave * 16 + l16) * 136 + dm * 16 + quad * 4 + 2 * hh] = pv;
        }
    __syncthreads();
#pragma unroll
    for (int i = 0; i < 4; i++) {
        int c  = i * 64 + lane;
        int r2 = c >> 4, ch = c & 15;
        uint4 v = *(const uint4*)&Ot[(size_t)(wave * 16 + r2) * 136 + ch * 8];
        *(uint4*)(O + (size_t)(b * SEQ + q0 + (wave & 3) * 16 + r2) * (NH * HD) + h * HD + ch * 8) = v;
    }
#undef STAGE_LOAD
#undef STAGE_WRITE
}

// ---------------------------------------------------------------------------
extern "C" void kernel_launch(void* const* d_in, const int* in_sizes, int n_in,
                              void* d_out, int out_size, void* d_ws, size_t ws_size,
                              hipStream_t stream)
{
    const float* x  = (const float*)d_in[0];
    const float* fc = (const float*)d_in[1];
    const float* fs = (const float*)d_in[2];
    const float* wq = (const float*)d_in[3];
    const float* wk = (const float*)d_in[4];
    const float* wv = (const float*)d_in[5];
    const float* wo = (const float*)d_in[6];
    float* out = (float*)d_out;

    const int BS = 2 * SEQ;  // 4096 rows
    char* ws = (char*)d_ws;
    // workspace layout (112 MB):
    //   [0,32M)    q     4096x4096 bf16
    //   [32,40M)   k     4096x1024 bf16
    //   [40,48M)   vT    [b][kvh][d][2048] bf16
    //   [48,80M)   xb (x in bf16)  -- aliased with attn (xb dead before flash)
    //   [80,112M)  wb    shared converted-weight slot (wq/wk/wv/wo in turn)
    __hip_bfloat16* q    = (__hip_bfloat16*)(ws);
    __hip_bfloat16* k    = (__hip_bfloat16*)(ws + 33554432ull);
    __hip_bfloat16* vT   = (__hip_bfloat16*)(ws + 41943040ull);
    __hip_bfloat16* xb   = (__hip_bfloat16*)(ws + 50331648ull);
    __hip_bfloat16* attn = xb;  // alias: xb dead once projections are done
    __hip_bfloat16* wb   = (__hip_bfloat16*)(ws + 83886080ull);

    cvt_bf16<<<2048, 256, 0, stream>>>(x,  xb, (BS * 4096) / 8);
    cvt_bf16<<<2048, 256, 0, stream>>>(wq, wb, (4096 * 4096) / 8);
    gemm_bt<__hip_bfloat16, false><<<dim3(32, 32), 256, 0, stream>>>(xb, wb, q,  BS, NH * HD,  4096);
    cvt_bf16<<<2048, 256, 0, stream>>>(wk, wb, (1024 * 4096) / 8);
    gemm_bt<__hip_bfloat16, false><<<dim3(8, 32),  256, 0, stream>>>(xb, wb, k,  BS, NKV * HD, 4096);
    cvt_bf16<<<2048, 256, 0, stream>>>(wv, wb, (1024 * 4096) / 8);
    gemm_bt<__hip_bfloat16, true ><<<dim3(8, 32),  256, 0, stream>>>(xb, wb, vT, BS, NKV * HD, 4096);

    {
        int npq = BS * NH * 64;
        rope_kernel<<<(npq + 255) / 256, 256, 0, stream>>>(q, fc, fs, npq, 11);
        int npk = BS * NKV * 64;
        rope_kernel<<<(npk + 255) / 256, 256, 0, stream>>>(k, fc, fs, npk, 9);
    }

    flash_kernel<<<dim3(SEQ / 64, NH / 2, 2), 512, 0, stream>>>(q, k, vT, attn);

    cvt_bf16<<<2048, 256, 0, stream>>>(wo, wb, (4096 * 4096) / 8);
    gemm_bt<float, false><<<dim3(32, 32), 256, 0, stream>>>(attn, wb, out, BS, NH * HD, 4096);
}

// Round 3
// 962.719 us; speedup vs baseline: 1.2957x; 1.0633x over previous
//
#include <hip/hip_runtime.h>
#include <hip/hip_bf16.h>

typedef short short8_t __attribute__((ext_vector_type(8)));
typedef float float4_t __attribute__((ext_vector_type(4)));

#define MFMA16(A, B, C) __builtin_amdgcn_mfma_f32_16x16x32_bf16((A), (B), (C), 0, 0, 0)

#define SEQ 2048
#define HD 128
#define NH 32
#define NKV 8

__device__ inline short f2bs(float f) {
    union { __hip_bfloat16 h; short s; } u;
    u.h = __float2bfloat16(f);
    return u.s;
}

__device__ inline short8_t load8(const __hip_bfloat16* p) {
    return *(const short8_t*)p;
}
__device__ inline short8_t load8(const float* p) {
    float4_t a = *(const float4_t*)p;
    float4_t b = *(const float4_t*)(p + 4);
    short8_t r;
    r[0] = f2bs(a[0]); r[1] = f2bs(a[1]); r[2] = f2bs(a[2]); r[3] = f2bs(a[3]);
    r[4] = f2bs(b[0]); r[5] = f2bs(b[1]); r[6] = f2bs(b[2]); r[7] = f2bs(b[3]);
    return r;
}

__device__ inline void store_c(__hip_bfloat16* p, float v) { *p = __float2bfloat16(v); }
__device__ inline void store_c(float* p, float v)          { *p = v; }

// async global->LDS DMA, 16B per lane. LDS dest must be WAVE-UNIFORM base;
// hardware adds lane*16 (guide §5 caveat, m104/m108).
__device__ __forceinline__ void gld_lds16(const __hip_bfloat16* g, __hip_bfloat16* l) {
    __builtin_amdgcn_global_load_lds(
        (const __attribute__((address_space(1))) unsigned int*)g,
        (__attribute__((address_space(3))) unsigned int*)l,
        16, 0, 0);
}

// ---------------------------------------------------------------------------
// fp32 -> bf16 conversion pass (memory-bound, float4 loads, 16B/lane).
// ---------------------------------------------------------------------------
__global__ __launch_bounds__(256) void cvt_bf16(
    const float* __restrict__ in, __hip_bfloat16* __restrict__ out, int n8)
{
    int stride = gridDim.x * 256;
    for (int i = blockIdx.x * 256 + threadIdx.x; i < n8; i += stride) {
        short8_t r = load8(in + (size_t)i * 8);
        *(short8_t*)(out + (size_t)i * 8) = r;
    }
}

// ---------------------------------------------------------------------------
// C[m][n] = sum_k A[m][k] * B[n][k]  (bf16 operands, row-major K-contiguous).
// m97 structure: 128x128 tile, BK=32, linear LDS, global_load_lds width=16,
// 2 barriers per K-step. If TRC: store transposed per-batch for V^T.
// ---------------------------------------------------------------------------
template <typename TC, bool TRC = false>
__global__ __launch_bounds__(256) void gemm_bt(
    const __hip_bfloat16* __restrict__ A,
    const __hip_bfloat16* __restrict__ B,
    TC* __restrict__ C,
    int M, int N, int K)
{
    __shared__ __hip_bfloat16 As[128 * 32];
    __shared__ __hip_bfloat16 Bs[128 * 32];

    const int tid  = threadIdx.x;
    const int wave = tid >> 6;
    const int lane = tid & 63;
    const int quad = lane >> 4;
    const int l16  = lane & 15;
    const int m0 = blockIdx.y * 128;
    const int n0 = blockIdx.x * 128;
    const int wm = (wave >> 1) * 64;
    const int wn = (wave & 1) * 64;

    const int row0 = tid >> 2;
    const int col0 = (tid & 3) * 8;

    const __hip_bfloat16* Abase = A + (size_t)m0 * K;
    const __hip_bfloat16* Bbase = B + (size_t)n0 * K;
    __hip_bfloat16* AsW = As + wave * 512;
    __hip_bfloat16* BsW = Bs + wave * 512;

    float4_t acc[4][4] = {};

    for (int k0 = 0; k0 < K; k0 += 32) {
        __syncthreads();
        gld_lds16(Abase + (size_t)row0        * K + k0 + col0, AsW);
        gld_lds16(Abase + (size_t)(row0 + 64) * K + k0 + col0, AsW + 2048);
        gld_lds16(Bbase + (size_t)row0        * K + k0 + col0, BsW);
        gld_lds16(Bbase + (size_t)(row0 + 64) * K + k0 + col0, BsW + 2048);
        __syncthreads();

        short8_t af[4], bf[4];
#pragma unroll
        for (int t = 0; t < 4; t++)
            af[t] = *(const short8_t*)&As[(wm + t * 16 + l16) * 32 + quad * 8];
#pragma unroll
        for (int t = 0; t < 4; t++)
            bf[t] = *(const short8_t*)&Bs[(wn + t * 16 + l16) * 32 + quad * 8];
#pragma unroll
        for (int mt = 0; mt < 4; mt++)
#pragma unroll
            for (int nt = 0; nt < 4; nt++)
                acc[mt][nt] = MFMA16(af[mt], bf[nt], acc[mt][nt]);
    }

#pragma unroll
    for (int mt = 0; mt < 4; mt++)
#pragma unroll
        for (int nt = 0; nt < 4; nt++)
#pragma unroll
            for (int r = 0; r < 4; r++) {
                int row = m0 + wm + mt * 16 + quad * 4 + r;
                int col = n0 + wn + nt * 16 + l16;
                if constexpr (TRC) {
                    int bb = row >> 11, ss = row & (SEQ - 1);
                    C[((size_t)bb * N + col) * SEQ + ss] = __float2bfloat16(acc[mt][nt][r]);
                } else {
                    store_c(&C[(size_t)row * N + col], acc[mt][nt][r]);
                }
            }
}

// ---------------------------------------------------------------------------
// RoPE in-place; freqs fp32 [SEQ][64].
// ---------------------------------------------------------------------------
__global__ __launch_bounds__(256) void rope_kernel(
    __hip_bfloat16* __restrict__ x,
    const float* __restrict__ cs,
    const float* __restrict__ sn,
    int npairs, int shift)
{
    int pi = blockIdx.x * 256 + threadIdx.x;
    if (pi >= npairs) return;
    int cols = 1 << shift;
    int cp   = pi & (cols - 1);
    int row  = pi >> shift;
    int d    = cp & 63;
    int pos  = row & (SEQ - 1);
    float c = cs[pos * 64 + d];
    float s = sn[pos * 64 + d];
    __hip_bfloat16* p = x + (((size_t)row) << (shift + 1)) + (size_t)cp * 2;
    float x0 = __bfloat162float(p[0]);
    float x1 = __bfloat162float(p[1]);
    p[0] = __float2bfloat16(x0 * c - x1 * s);
    p[1] = __float2bfloat16(x0 * s + x1 * c);
}

// ---------------------------------------------------------------------------
// Causal GQA flash attention, swapped-operand layout.
// Grid: (S/64, NH/2, B), block 512 = 8 waves covering TWO heads that share
// one kvh (h = 2*by + (wave>>2)); one K/V stage feeds 128 q-rows of MFMA.
//
// Load-balance: the whole grid (1024 blocks) is co-resident (4 blocks/CU),
// and a CU's 4 blocks share the same blockIdx.x. qt = 31-x gave every CU
// 4 identical-length blocks (range 4..128 iters/CU -> 20% occupancy).
// Remap qt = (x + y + 16z) mod 32: co-resident set {a,a+8,a+16,a+24} ->
// per-CU work in [52,80] iters. Bijective in x per head, so tiling is valid.
// ---------------------------------------------------------------------------
__global__ __launch_bounds__(512, 4) void flash_kernel(
    const __hip_bfloat16* __restrict__ Q,
    const __hip_bfloat16* __restrict__ Km,
    const __hip_bfloat16* __restrict__ VT,
    __hip_bfloat16* __restrict__ O)
{
    // Ks[64][136] | Vt[128][72]  (35840 B); epilogue reuses as Ot[128][136].
    __shared__ __hip_bfloat16 smem[64 * 136 + 128 * 72];
    __hip_bfloat16* Ks = smem;
    __hip_bfloat16* Vt = smem + 64 * 136;

    const int tid  = threadIdx.x;
    const int wave = tid >> 6;
    const int lane = tid & 63;
    const int quad = lane >> 4;
    const int l16  = lane & 15;
    const int qt = ((int)blockIdx.x + (int)blockIdx.y + ((int)blockIdx.z << 4)) & 31;
    const int h  = (int)blockIdx.y * 2 + (wave >> 2);
    const int b  = blockIdx.z;
    const int kvh = blockIdx.y >> 1;                      // same for both heads
    const int q0  = qt * 64;
    const float scale = 0.08838834764831845f;  // 1/sqrt(128)
    const int qrow = q0 + (wave & 3) * 16 + l16;          // this lane's q row

    // Q B-fragments straight from global
    short8_t qf[4];
    {
        const __hip_bfloat16* qp = Q + (size_t)(b * SEQ + qrow) * (NH * HD) + h * HD + quad * 8;
#pragma unroll
        for (int kk = 0; kk < 4; kk++)
            qf[kk] = *(const short8_t*)(qp + kk * 32);
    }

    float4_t acc[8] = {};          // O^T: acc[dm], d = dm*16 + quad*4 + r, q = l16
    float m_st = -1e30f, l_st = 0.f;

    const __hip_bfloat16* vbase = VT + ((size_t)(b * NKV + kvh) * HD) * SEQ;
    const __hip_bfloat16* kbase = Km + (size_t)(b * SEQ) * (NKV * HD) + kvh * HD;

    // staging indices (512 threads: K tile 64x128 = 2 uint4/thread, V same)
    const int krow0 = tid >> 4;          // 0..31
    const int kseg  = (tid & 15) * 8;
    const int vd0   = tid >> 3;          // 0..63
    const int vsl   = (tid & 7) * 8;

    uint4 kr0, kr1, vr0, vr1;
#define STAGE_LOAD(KT)                                                              \
    {                                                                               \
        kr0 = *(const uint4*)(kbase + (size_t)((KT) * 64 + krow0)      * (NKV * HD) + kseg); \
        kr1 = *(const uint4*)(kbase + (size_t)((KT) * 64 + krow0 + 32) * (NKV * HD) + kseg); \
        vr0 = *(const uint4*)(vbase + (size_t)vd0        * SEQ + (KT) * 64 + vsl);  \
        vr1 = *(const uint4*)(vbase + (size_t)(vd0 + 64) * SEQ + (KT) * 64 + vsl);  \
    }
#define STAGE_WRITE()                                         \
    {                                                         \
        *(uint4*)&Ks[(size_t)krow0        * 136 + kseg] = kr0; \
        *(uint4*)&Ks[(size_t)(krow0 + 32) * 136 + kseg] = kr1; \
        *(uint4*)&Vt[(size_t)vd0          * 72  + vsl]  = vr0; \
        *(uint4*)&Vt[(size_t)(vd0 + 64)   * 72  + vsl]  = vr1; \
    }

    STAGE_LOAD(0);
    STAGE_WRITE();
    __syncthreads();

    for (int kt = 0; kt <= qt; kt++) {
        const bool last = (kt == qt);
        if (!last) STAGE_LOAD(kt + 1);   // issue early; lands under compute

        // S^T[key][q]
        float4_t st[4] = {};
        __builtin_amdgcn_s_setprio(1);
#pragma unroll
        for (int kk = 0; kk < 4; kk++)
#pragma unroll
            for (int mt = 0; mt < 4; mt++) {
                short8_t kf = *(const short8_t*)&Ks[(size_t)(mt * 16 + l16) * 136 + kk * 32 + quad * 8];
                st[mt] = MFMA16(kf, qf[kk], st[mt]);
            }
        __builtin_amdgcn_s_setprio(0);

        // softmax over this lane's 16 keys; mask only on the diagonal tile
        float mx = -1e30f;
        if (last) {
#pragma unroll
            for (int mt = 0; mt < 4; mt++)
#pragma unroll
                for (int r = 0; r < 4; r++) {
                    int key = kt * 64 + mt * 16 + quad * 4 + r;
                    float s = st[mt][r] * scale;
                    if (key > qrow) s = -1e30f;
                    st[mt][r] = s;
                    mx = fmaxf(mx, s);
                }
        } else {
#pragma unroll
            for (int mt = 0; mt < 4; mt++)
#pragma unroll
                for (int r = 0; r < 4; r++) {
                    float s = st[mt][r] * scale;
                    st[mt][r] = s;
                    mx = fmaxf(mx, s);
                }
        }
        mx = fmaxf(mx, __shfl_xor(mx, 16, 64));
        mx = fmaxf(mx, __shfl_xor(mx, 32, 64));

        // defer-max: skip rescale while growth bounded (P <= e^8, f32-safe)
        float mcur;
        if (__all(mx <= m_st + 8.f)) {
            mcur = m_st;
        } else {
            float mnew  = fmaxf(m_st, mx);
            float alpha = __expf(m_st - mnew);
            l_st *= alpha;
#pragma unroll
            for (int dm = 0; dm < 8; dm++)
                acc[dm] *= alpha;
            m_st = mnew;
            mcur = mnew;
        }

        // exp + pack directly into bf16 pairs (keys mt*16 + quad*4 + {2h,2h+1})
        uint32_t pk[4][2];
        float rsum = 0.f;
#pragma unroll
        for (int mt = 0; mt < 4; mt++)
#pragma unroll
            for (int hh = 0; hh < 2; hh++) {
                float p0 = __expf(st[mt][2 * hh]     - mcur);
                float p1 = __expf(st[mt][2 * hh + 1] - mcur);
                rsum += p0 + p1;
                pk[mt][hh] = (uint32_t)(unsigned short)f2bs(p0) |
                             ((uint32_t)(unsigned short)f2bs(p1) << 16);
            }
        rsum += __shfl_xor(rsum, 16, 64);
        rsum += __shfl_xor(rsum, 32, 64);
        l_st += rsum;

        // build P^T B-fragments via cross-lane permutes
        const int src0 = ((quad & 1) * 2) * 16 + l16;
        const int src1 = src0 + 16;
        const bool hi_mt = (quad >> 1) != 0;
#pragma unroll
        for (int kk2 = 0; kk2 < 2; kk2++) {
            uint32_t a0 = (uint32_t)__shfl((int)pk[kk2 * 2][0],     src0, 64);
            uint32_t a1 = (uint32_t)__shfl((int)pk[kk2 * 2][1],     src0, 64);
            uint32_t a2 = (uint32_t)__shfl((int)pk[kk2 * 2][0],     src1, 64);
            uint32_t a3 = (uint32_t)__shfl((int)pk[kk2 * 2][1],     src1, 64);
            uint32_t b0 = (uint32_t)__shfl((int)pk[kk2 * 2 + 1][0], src0, 64);
            uint32_t b1 = (uint32_t)__shfl((int)pk[kk2 * 2 + 1][1], src0, 64);
            uint32_t b2 = (uint32_t)__shfl((int)pk[kk2 * 2 + 1][0], src1, 64);
            uint32_t b3 = (uint32_t)__shfl((int)pk[kk2 * 2 + 1][1], src1, 64);
            union { uint32_t u[4]; short8_t v; } pf;
            pf.u[0] = hi_mt ? b0 : a0;
            pf.u[1] = hi_mt ? b1 : a1;
            pf.u[2] = hi_mt ? b2 : a2;
            pf.u[3] = hi_mt ? b3 : a3;
            __builtin_amdgcn_s_setprio(1);
#pragma unroll
            for (int dm = 0; dm < 8; dm++) {
                short8_t vf = *(const short8_t*)&Vt[(size_t)(dm * 16 + l16) * 72 + kk2 * 32 + quad * 8];
                acc[dm] = MFMA16(vf, pf.v, acc[dm]);
            }
            __builtin_amdgcn_s_setprio(0);
        }

        __syncthreads();               // all waves done reading tile kt
        if (!last) {
            STAGE_WRITE();             // waits vmcnt internally (reg use)
            __syncthreads();           // tile kt+1 visible
        }
    }

    // epilogue: O^T -> O via LDS transpose; reuse smem as Ot[128][136]
    __hip_bfloat16* Ot = smem;
    float inv_l = 1.f / l_st;
#pragma unroll
    for (int dm = 0; dm < 8; dm++)
#pragma unroll
        for (int hh = 0; hh < 2; hh++) {
            uint32_t pv = (uint32_t)(unsigned short)f2bs(acc[dm][2 * hh] * inv_l) |
                          ((uint32_t)(unsigned short)f2bs(acc[dm][2 * hh + 1] * inv_l) << 16);
            *(uint32_t*)&Ot[(size_t)(wave * 16 + l16) * 136 + dm * 16 + quad * 4 + 2 * hh] = pv;
        }
    __syncthreads();
#pragma unroll
    for (int i = 0; i < 4; i++) {
        int c  = i * 64 + lane;
        int r2 = c >> 4, ch = c & 15;
        uint4 v = *(const uint4*)&Ot[(size_t)(wave * 16 + r2) * 136 + ch * 8];
        *(uint4*)(O + (size_t)(b * SEQ + q0 + (wave & 3) * 16 + r2) * (NH * HD) + h * HD + ch * 8) = v;
    }
#undef STAGE_LOAD
#undef STAGE_WRITE
}

// ---------------------------------------------------------------------------
extern "C" void kernel_launch(void* const* d_in, const int* in_sizes, int n_in,
                              void* d_out, int out_size, void* d_ws, size_t ws_size,
                              hipStream_t stream)
{
    const float* x  = (const float*)d_in[0];
    const float* fc = (const float*)d_in[1];
    const float* fs = (const float*)d_in[2];
    const float* wq = (const float*)d_in[3];
    const float* wk = (const float*)d_in[4];
    const float* wv = (const float*)d_in[5];
    const float* wo = (const float*)d_in[6];
    float* out = (float*)d_out;

    const int BS = 2 * SEQ;  // 4096 rows
    char* ws = (char*)d_ws;
    // workspace layout (112 MB):
    //   [0,32M)    q     4096x4096 bf16
    //   [32,40M)   k     4096x1024 bf16
    //   [40,48M)   vT    [b][kvh][d][2048] bf16
    //   [48,80M)   xb (x in bf16)  -- aliased with attn (xb dead before flash)
    //   [80,112M)  wb    shared converted-weight slot (wq/wk/wv/wo in turn)
    __hip_bfloat16* q    = (__hip_bfloat16*)(ws);
    __hip_bfloat16* k    = (__hip_bfloat16*)(ws + 33554432ull);
    __hip_bfloat16* vT   = (__hip_bfloat16*)(ws + 41943040ull);
    __hip_bfloat16* xb   = (__hip_bfloat16*)(ws + 50331648ull);
    __hip_bfloat16* attn = xb;  // alias: xb dead once projections are done
    __hip_bfloat16* wb   = (__hip_bfloat16*)(ws + 83886080ull);

    cvt_bf16<<<2048, 256, 0, stream>>>(x,  xb, (BS * 4096) / 8);
    cvt_bf16<<<2048, 256, 0, stream>>>(wq, wb, (4096 * 4096) / 8);
    gemm_bt<__hip_bfloat16, false><<<dim3(32, 32), 256, 0, stream>>>(xb, wb, q,  BS, NH * HD,  4096);
    cvt_bf16<<<2048, 256, 0, stream>>>(wk, wb, (1024 * 4096) / 8);
    gemm_bt<__hip_bfloat16, false><<<dim3(8, 32),  256, 0, stream>>>(xb, wb, k,  BS, NKV * HD, 4096);
    cvt_bf16<<<2048, 256, 0, stream>>>(wv, wb, (1024 * 4096) / 8);
    gemm_bt<__hip_bfloat16, true ><<<dim3(8, 32),  256, 0, stream>>>(xb, wb, vT, BS, NKV * HD, 4096);

    {
        int npq = BS * NH * 64;
        rope_kernel<<<(npq + 255) / 256, 256, 0, stream>>>(q, fc, fs, npq, 11);
        int npk = BS * NKV * 64;
        rope_kernel<<<(npk + 255) / 256, 256, 0, stream>>>(k, fc, fs, npk, 9);
    }

    flash_kernel<<<dim3(SEQ / 64, NH / 2, 2), 512, 0, stream>>>(q, k, vT, attn);

    cvt_bf16<<<2048, 256, 0, stream>>>(wo, wb, (4096 * 4096) / 8);
    gemm_bt<float, false><<<dim3(32, 32), 256, 0, stream>>>(attn, wb, out, BS, NH * HD, 4096);
}

// Round 5
// 806.252 us; speedup vs baseline: 1.5471x; 1.1941x over previous
//
#include <hip/hip_runtime.h>
#include <hip/hip_bf16.h>

typedef short short8_t __attribute__((ext_vector_type(8)));
typedef float float4_t __attribute__((ext_vector_type(4)));

#define MFMA16(A, B, C) __builtin_amdgcn_mfma_f32_16x16x32_bf16((A), (B), (C), 0, 0, 0)

#define SEQ 2048
#define HD 128
#define NH 32
#define NKV 8

__device__ inline short f2bs(float f) {
    union { __hip_bfloat16 h; short s; } u;
    u.h = __float2bfloat16(f);
    return u.s;
}

__device__ inline short8_t load8(const __hip_bfloat16* p) {
    return *(const short8_t*)p;
}
__device__ inline short8_t load8(const float* p) {
    float4_t a = *(const float4_t*)p;
    float4_t b = *(const float4_t*)(p + 4);
    short8_t r;
    r[0] = f2bs(a[0]); r[1] = f2bs(a[1]); r[2] = f2bs(a[2]); r[3] = f2bs(a[3]);
    r[4] = f2bs(b[0]); r[5] = f2bs(b[1]); r[6] = f2bs(b[2]); r[7] = f2bs(b[3]);
    return r;
}

__device__ inline void store_c(__hip_bfloat16* p, float v) { *p = __float2bfloat16(v); }
__device__ inline void store_c(float* p, float v)          { *p = v; }

// async global->LDS DMA, 16B per lane. LDS dest must be WAVE-UNIFORM base;
// hardware adds lane*16 (guide §5 caveat, m104/m108).
__device__ __forceinline__ void gld_lds16(const __hip_bfloat16* g, __hip_bfloat16* l) {
    __builtin_amdgcn_global_load_lds(
        (const __attribute__((address_space(1))) unsigned int*)g,
        (__attribute__((address_space(3))) unsigned int*)l,
        16, 0, 0);
}

// ---------------------------------------------------------------------------
// fp32 -> bf16 conversion pass (memory-bound, float4 loads, 16B/lane).
// ---------------------------------------------------------------------------
__global__ __launch_bounds__(256) void cvt_bf16(
    const float* __restrict__ in, __hip_bfloat16* __restrict__ out, int n8)
{
    int stride = gridDim.x * 256;
    for (int i = blockIdx.x * 256 + threadIdx.x; i < n8; i += stride) {
        short8_t r = load8(in + (size_t)i * 8);
        *(short8_t*)(out + (size_t)i * 8) = r;
    }
}

// ---------------------------------------------------------------------------
// 128x128 m97-structure GEMM (kept for the N=1024 K/V projections).
// C[m][n] = sum_k A[m][k]*B[n][k]. If TRC: store V^T per-batch.
// ---------------------------------------------------------------------------
template <typename TC, bool TRC = false>
__global__ __launch_bounds__(256) void gemm_bt(
    const __hip_bfloat16* __restrict__ A,
    const __hip_bfloat16* __restrict__ B,
    TC* __restrict__ C,
    int M, int N, int K)
{
    __shared__ __hip_bfloat16 As[128 * 32];
    __shared__ __hip_bfloat16 Bs[128 * 32];

    const int tid  = threadIdx.x;
    const int wave = tid >> 6;
    const int lane = tid & 63;
    const int quad = lane >> 4;
    const int l16  = lane & 15;
    const int m0 = blockIdx.y * 128;
    const int n0 = blockIdx.x * 128;
    const int wm = (wave >> 1) * 64;
    const int wn = (wave & 1) * 64;

    const int row0 = tid >> 2;
    const int col0 = (tid & 3) * 8;

    const __hip_bfloat16* Abase = A + (size_t)m0 * K;
    const __hip_bfloat16* Bbase = B + (size_t)n0 * K;
    __hip_bfloat16* AsW = As + wave * 512;
    __hip_bfloat16* BsW = Bs + wave * 512;

    float4_t acc[4][4] = {};

    for (int k0 = 0; k0 < K; k0 += 32) {
        __syncthreads();
        gld_lds16(Abase + (size_t)row0        * K + k0 + col0, AsW);
        gld_lds16(Abase + (size_t)(row0 + 64) * K + k0 + col0, AsW + 2048);
        gld_lds16(Bbase + (size_t)row0        * K + k0 + col0, BsW);
        gld_lds16(Bbase + (size_t)(row0 + 64) * K + k0 + col0, BsW + 2048);
        __syncthreads();

        short8_t af[4], bf[4];
#pragma unroll
        for (int t = 0; t < 4; t++)
            af[t] = *(const short8_t*)&As[(wm + t * 16 + l16) * 32 + quad * 8];
#pragma unroll
        for (int t = 0; t < 4; t++)
            bf[t] = *(const short8_t*)&Bs[(wn + t * 16 + l16) * 32 + quad * 8];
#pragma unroll
        for (int mt = 0; mt < 4; mt++)
#pragma unroll
            for (int nt = 0; nt < 4; nt++)
                acc[mt][nt] = MFMA16(af[mt], bf[nt], acc[mt][nt]);
    }

#pragma unroll
    for (int mt = 0; mt < 4; mt++)
#pragma unroll
        for (int nt = 0; nt < 4; nt++)
#pragma unroll
            for (int r = 0; r < 4; r++) {
                int row = m0 + wm + mt * 16 + quad * 4 + r;
                int col = n0 + wn + nt * 16 + l16;
                if constexpr (TRC) {
                    int bb = row >> 11, ss = row & (SEQ - 1);
                    C[((size_t)bb * N + col) * SEQ + ss] = __float2bfloat16(acc[mt][nt][r]);
                } else {
                    store_c(&C[(size_t)row * N + col], acc[mt][nt][r]);
                }
            }
}

// ---------------------------------------------------------------------------
// 256x256 8-phase GEMM (T2 swizzle + T3/T4 counted vmcnt + T5 setprio).
// C[m][n] = sum_k A[m][k]*B[n][k], bf16 in, K multiple of 128.
// 8 waves (2M x 4N); wave tile 128x64 interleaved across tile halves:
//   row(qm,mt) = qm*128 + wm*64 + mt*16, col(qn,nt) = qn*128 + wn*32 + nt*16
// so each phase (one quadrant x K=64) consumes exactly one 128-row half-tile
// of A and B, which dies at that phase's end barrier -> staged over in place.
// LDS 128KB = 2 K-tile buffers x (A,B) x 256x64 bf16. Storage swizzle:
// LDS[row][s] holds global 16B-chunk (s ^ (row&7)) -> ds_read_b128 spreads
// 16 rows over 8 bank-slots (2-way = free). DMA dest stays linear (m104),
// source address carries the inverse permutation (rule #21).
// Stage schedule (T0=2i,T1=2i+1): P1:B1(T1,H1) P2:A1(T1,H1) P3:A0(T0+2,H0)
// P4:B0(T0+2,H0) P5:B0(T0+2,H1) P6:A0(T0+2,H1) P7:A1(T1+2,H0) P8:B1(T1+2,H0)
// vmcnt(4) at P4/P8 only. Ledger-verified: every half-tile retires >=1 wait
// before its first read; every stage issues after the death barrier of the
// data it overwrites; in-phase DMA writes are half-disjoint from reads.
// All barriers carry compiler memory fences (zero instructions) so hipcc
// cannot move ds_reads / DMA intrinsics across phase boundaries (m152 class).
// ---------------------------------------------------------------------------
template <typename TC>
__global__ __launch_bounds__(512, 2) void gemm256(
    const __hip_bfloat16* __restrict__ A,
    const __hip_bfloat16* __restrict__ B,
    TC* __restrict__ C,
    int M, int N, int K)
{
    __shared__ __hip_bfloat16 lds[65536];   // 128 KiB
    __hip_bfloat16* ldsA0 = lds;
    __hip_bfloat16* ldsB0 = lds + 16384;
    __hip_bfloat16* ldsA1 = lds + 32768;
    __hip_bfloat16* ldsB1 = lds + 49152;

    const int tid  = threadIdx.x;
    const int wave = tid >> 6;
    const int lane = tid & 63;
    const int quad = lane >> 4;
    const int l16  = lane & 15;
    const int wm = wave >> 2;      // 0..1
    const int wn = wave & 3;       // 0..3
    const int m0 = blockIdx.y * 256;
    const int n0 = blockIdx.x * 256;

    const __hip_bfloat16* Abase = A + (size_t)m0 * K;
    const __hip_bfloat16* Bbase = B + (size_t)n0 * K;

    float4_t acc[8][4] = {};
    short8_t af[4][2], bf[2][2];

#define FENCE  asm volatile("" ::: "memory")
#define BAR    { FENCE; __builtin_amdgcn_s_barrier(); FENCE; }
#define LGKM0  { asm volatile("s_waitcnt lgkmcnt(0)" ::: "memory");          \
                 __builtin_amdgcn_sched_barrier(0); }
#define LGKM8  asm volatile("s_waitcnt lgkmcnt(8)" ::: "memory")
#define VM4    asm volatile("s_waitcnt vmcnt(4)" ::: "memory")
#define VM0    asm volatile("s_waitcnt vmcnt(0)" ::: "memory")

// stage one half-tile (128 rows x 64 cols) of tile T, half H, operand GBASE
// into LDS tile LTILE. Linear DMA dest; source pre-permuted (s ^ r&7).
#define STAGE(GBASE, LTILE, T, H)                                            \
    {                                                                        \
        _Pragma("unroll")                                                    \
        for (int j = 0; j < 2; j++) {                                        \
            int c = j * 512 + tid;                                           \
            int r = c >> 3, s = c & 7;                                       \
            gld_lds16((GBASE) + (size_t)((H) * 128 + r) * K + (T) * 64 +     \
                          ((s ^ (r & 7)) * 8),                               \
                      (LTILE) + (H) * 8192 + j * 4096 + wave * 512);         \
        }                                                                    \
    }

#define LDA_(QM, ABASE)                                                      \
    {                                                                        \
        _Pragma("unroll")                                                    \
        for (int mt = 0; mt < 4; mt++)                                       \
            _Pragma("unroll")                                                \
            for (int kk = 0; kk < 2; kk++) {                                 \
                int row = (QM) * 128 + wm * 64 + mt * 16 + l16;              \
                int sc  = (kk * 4 + quad) ^ (row & 7);                       \
                af[mt][kk] = *(const short8_t*)&(ABASE)[row * 64 + sc * 8];  \
            }                                                                \
    }

#define LDB_(QN, BBASE)                                                      \
    {                                                                        \
        _Pragma("unroll")                                                    \
        for (int nt = 0; nt < 2; nt++)                                       \
            _Pragma("unroll")                                                \
            for (int kk = 0; kk < 2; kk++) {                                 \
                int row = (QN) * 128 + wn * 32 + nt * 16 + l16;              \
                int sc  = (kk * 4 + quad) ^ (row & 7);                       \
                bf[nt][kk] = *(const short8_t*)&(BBASE)[row * 64 + sc * 8];  \
            }                                                                \
    }

#define QMM(QM, QN)                                                          \
    __builtin_amdgcn_s_setprio(1);                                           \
    _Pragma("unroll")                                                        \
    for (int mt = 0; mt < 4; mt++)                                           \
        _Pragma("unroll")                                                    \
        for (int nt = 0; nt < 2; nt++)                                       \
            _Pragma("unroll")                                                \
            for (int kk = 0; kk < 2; kk++)                                   \
                acc[(QM) * 4 + mt][(QN) * 2 + nt] =                          \
                    MFMA16(af[mt][kk], bf[nt][kk],                           \
                           acc[(QM) * 4 + mt][(QN) * 2 + nt]);               \
    __builtin_amdgcn_s_setprio(0);

    // prologue: tile 0 complete + A1,B1 half0 of tile 1 (12 loads/thread)
    STAGE(Abase, ldsA0, 0, 0);
    STAGE(Bbase, ldsB0, 0, 0);
    STAGE(Abase, ldsA0, 0, 1);
    STAGE(Bbase, ldsB0, 0, 1);
    STAGE(Abase, ldsA1, 1, 0);
    STAGE(Bbase, ldsB1, 1, 0);
    VM4;                       // retire 8 oldest = tile 0 fully landed
    BAR;

    const int NIT = (K >> 7);  // K/128 double-K-tile iterations
#pragma unroll 1
    for (int i = 0; i < NIT - 1; i++) {
        const int T0 = 2 * i, T1 = 2 * i + 1;
        // P1
        LDA_(0, ldsA0); LDB_(0, ldsB0);
        STAGE(Bbase, ldsB1, T1, 1);
        LGKM8; BAR; LGKM0; QMM(0, 0); BAR;
        // P2
        LDB_(1, ldsB0);
        STAGE(Abase, ldsA1, T1, 1);
        BAR; LGKM0; QMM(0, 1); BAR;
        // P3
        LDA_(1, ldsA0); LDB_(0, ldsB0);
        STAGE(Abase, ldsA0, T0 + 2, 0);
        LGKM8; BAR; LGKM0; QMM(1, 0); BAR;
        // P4
        LDB_(1, ldsB0);
        STAGE(Bbase, ldsB0, T0 + 2, 0);
        VM4; BAR; LGKM0; QMM(1, 1); BAR;
        // P5
        LDA_(0, ldsA1); LDB_(0, ldsB1);
        STAGE(Bbase, ldsB0, T0 + 2, 1);
        LGKM8; BAR; LGKM0; QMM(0, 0); BAR;
        // P6
        LDB_(1, ldsB1);
        STAGE(Abase, ldsA0, T0 + 2, 1);
        BAR; LGKM0; QMM(0, 1); BAR;
        // P7
        LDA_(1, ldsA1); LDB_(0, ldsB1);
        STAGE(Abase, ldsA1, T1 + 2, 0);
        LGKM8; BAR; LGKM0; QMM(1, 0); BAR;
        // P8
        LDB_(1, ldsB1);
        STAGE(Bbase, ldsB1, T1 + 2, 0);
        VM4; BAR; LGKM0; QMM(1, 1); BAR;
    }

    // peeled final iteration: stage only the last tile's H1 halves; drain
    // vmcnt fully at P4; tail phases have no further overwrites.
    {
        const int TL = 2 * NIT - 1;
        // P1
        LDA_(0, ldsA0); LDB_(0, ldsB0);
        STAGE(Bbase, ldsB1, TL, 1);
        LGKM8; BAR; LGKM0; QMM(0, 0); BAR;
        // P2
        LDB_(1, ldsB0);
        STAGE(Abase, ldsA1, TL, 1);
        BAR; LGKM0; QMM(0, 1); BAR;
        // P3
        LDA_(1, ldsA0); LDB_(0, ldsB0);
        LGKM8; BAR; LGKM0; QMM(1, 0); BAR;
        // P4
        LDB_(1, ldsB0);
        VM0; BAR; LGKM0; QMM(1, 1); BAR;
        // P5-P8: all data landed & stable; compiler tracks ds_read->MFMA deps
        LDA_(0, ldsA1); LDB_(0, ldsB1); QMM(0, 0);
        LDB_(1, ldsB1);                 QMM(0, 1);
        LDA_(1, ldsA1); LDB_(0, ldsB1); QMM(1, 0);
        LDB_(1, ldsB1);                 QMM(1, 1);
    }

    // epilogue
#pragma unroll
    for (int qm = 0; qm < 2; qm++)
#pragma unroll
        for (int mt = 0; mt < 4; mt++)
#pragma unroll
            for (int qn = 0; qn < 2; qn++)
#pragma unroll
                for (int nt = 0; nt < 2; nt++)
#pragma unroll
                    for (int r = 0; r < 4; r++) {
                        int row = m0 + qm * 128 + wm * 64 + mt * 16 + quad * 4 + r;
                        int col = n0 + qn * 128 + wn * 32 + nt * 16 + l16;
                        store_c(&C[(size_t)row * N + col], acc[qm * 4 + mt][qn * 2 + nt][r]);
                    }
#undef STAGE
#undef LDA_
#undef LDB_
#undef QMM
#undef FENCE
#undef BAR
#undef LGKM0
#undef LGKM8
#undef VM4
#undef VM0
}

// ---------------------------------------------------------------------------
// RoPE in-place; freqs fp32 [SEQ][64].
// ---------------------------------------------------------------------------
__global__ __launch_bounds__(256) void rope_kernel(
    __hip_bfloat16* __restrict__ x,
    const float* __restrict__ cs,
    const float* __restrict__ sn,
    int npairs, int shift)
{
    int pi = blockIdx.x * 256 + threadIdx.x;
    if (pi >= npairs) return;
    int cols = 1 << shift;
    int cp   = pi & (cols - 1);
    int row  = pi >> shift;
    int d    = cp & 63;
    int pos  = row & (SEQ - 1);
    float c = cs[pos * 64 + d];
    float s = sn[pos * 64 + d];
    __hip_bfloat16* p = x + (((size_t)row) << (shift + 1)) + (size_t)cp * 2;
    float x0 = __bfloat162float(p[0]);
    float x1 = __bfloat162float(p[1]);
    p[0] = __float2bfloat16(x0 * c - x1 * s);
    p[1] = __float2bfloat16(x0 * s + x1 * c);
}

// ---------------------------------------------------------------------------
// Causal GQA flash attention, swapped-operand layout (round-3 version:
// 8-wave 2-head blocks, async-stage split, qt stagger, defer-max).
// ---------------------------------------------------------------------------
__global__ __launch_bounds__(512, 4) void flash_kernel(
    const __hip_bfloat16* __restrict__ Q,
    const __hip_bfloat16* __restrict__ Km,
    const __hip_bfloat16* __restrict__ VT,
    __hip_bfloat16* __restrict__ O)
{
    __shared__ __hip_bfloat16 smem[64 * 136 + 128 * 72];
    __hip_bfloat16* Ks = smem;
    __hip_bfloat16* Vt = smem + 64 * 136;

    const int tid  = threadIdx.x;
    const int wave = tid >> 6;
    const int lane = tid & 63;
    const int quad = lane >> 4;
    const int l16  = lane & 15;
    const int qt = ((int)blockIdx.x + (int)blockIdx.y + ((int)blockIdx.z << 4)) & 31;
    const int h  = (int)blockIdx.y * 2 + (wave >> 2);
    const int b  = blockIdx.z;
    const int kvh = blockIdx.y >> 1;
    const int q0  = qt * 64;
    const float scale = 0.08838834764831845f;
    const int qrow = q0 + (wave & 3) * 16 + l16;

    short8_t qf[4];
    {
        const __hip_bfloat16* qp = Q + (size_t)(b * SEQ + qrow) * (NH * HD) + h * HD + quad * 8;
#pragma unroll
        for (int kk = 0; kk < 4; kk++)
            qf[kk] = *(const short8_t*)(qp + kk * 32);
    }

    float4_t acc[8] = {};
    float m_st = -1e30f, l_st = 0.f;

    const __hip_bfloat16* vbase = VT + ((size_t)(b * NKV + kvh) * HD) * SEQ;
    const __hip_bfloat16* kbase = Km + (size_t)(b * SEQ) * (NKV * HD) + kvh * HD;

    const int krow0 = tid >> 4;
    const int kseg  = (tid & 15) * 8;
    const int vd0   = tid >> 3;
    const int vsl   = (tid & 7) * 8;

    uint4 kr0, kr1, vr0, vr1;
#define STAGE_LOAD(KT)                                                              \
    {                                                                               \
        kr0 = *(const uint4*)(kbase + (size_t)((KT) * 64 + krow0)      * (NKV * HD) + kseg); \
        kr1 = *(const uint4*)(kbase + (size_t)((KT) * 64 + krow0 + 32) * (NKV * HD) + kseg); \
        vr0 = *(const uint4*)(vbase + (size_t)vd0        * SEQ + (KT) * 64 + vsl);  \
        vr1 = *(const uint4*)(vbase + (size_t)(vd0 + 64) * SEQ + (KT) * 64 + vsl);  \
    }
#define STAGE_WRITE()                                         \
    {                                                         \
        *(uint4*)&Ks[(size_t)krow0        * 136 + kseg] = kr0; \
        *(uint4*)&Ks[(size_t)(krow0 + 32) * 136 + kseg] = kr1; \
        *(uint4*)&Vt[(size_t)vd0          * 72  + vsl]  = vr0; \
        *(uint4*)&Vt[(size_t)(vd0 + 64)   * 72  + vsl]  = vr1; \
    }

    STAGE_LOAD(0);
    STAGE_WRITE();
    __syncthreads();

    for (int kt = 0; kt <= qt; kt++) {
        const bool last = (kt == qt);
        if (!last) STAGE_LOAD(kt + 1);

        float4_t st[4] = {};
        __builtin_amdgcn_s_setprio(1);
#pragma unroll
        for (int kk = 0; kk < 4; kk++)
#pragma unroll
            for (int mt = 0; mt < 4; mt++) {
                short8_t kf = *(const short8_t*)&Ks[(size_t)(mt * 16 + l16) * 136 + kk * 32 + quad * 8];
                st[mt] = MFMA16(kf, qf[kk], st[mt]);
            }
        __builtin_amdgcn_s_setprio(0);

        float mx = -1e30f;
        if (last) {
#pragma unroll
            for (int mt = 0; mt < 4; mt++)
#pragma unroll
                for (int r = 0; r < 4; r++) {
                    int key = kt * 64 + mt * 16 + quad * 4 + r;
                    float s = st[mt][r] * scale;
                    if (key > qrow) s = -1e30f;
                    st[mt][r] = s;
                    mx = fmaxf(mx, s);
                }
        } else {
#pragma unroll
            for (int mt = 0; mt < 4; mt++)
#pragma unroll
                for (int r = 0; r < 4; r++) {
                    float s = st[mt][r] * scale;
                    st[mt][r] = s;
                    mx = fmaxf(mx, s);
                }
        }
        mx = fmaxf(mx, __shfl_xor(mx, 16, 64));
        mx = fmaxf(mx, __shfl_xor(mx, 32, 64));

        float mcur;
        if (__all(mx <= m_st + 8.f)) {
            mcur = m_st;
        } else {
            float mnew  = fmaxf(m_st, mx);
            float alpha = __expf(m_st - mnew);
            l_st *= alpha;
#pragma unroll
            for (int dm = 0; dm < 8; dm++)
                acc[dm] *= alpha;
            m_st = mnew;
            mcur = mnew;
        }

        uint32_t pk[4][2];
        float rsum = 0.f;
#pragma unroll
        for (int mt = 0; mt < 4; mt++)
#pragma unroll
            for (int hh = 0; hh < 2; hh++) {
                float p0 = __expf(st[mt][2 * hh]     - mcur);
                float p1 = __expf(st[mt][2 * hh + 1] - mcur);
                rsum += p0 + p1;
                pk[mt][hh] = (uint32_t)(unsigned short)f2bs(p0) |
                             ((uint32_t)(unsigned short)f2bs(p1) << 16);
            }
        rsum += __shfl_xor(rsum, 16, 64);
        rsum += __shfl_xor(rsum, 32, 64);
        l_st += rsum;

        const int src0 = ((quad & 1) * 2) * 16 + l16;
        const int src1 = src0 + 16;
        const bool hi_mt = (quad >> 1) != 0;
#pragma unroll
        for (int kk2 = 0; kk2 < 2; kk2++) {
            uint32_t a0 = (uint32_t)__shfl((int)pk[kk2 * 2][0],     src0, 64);
            uint32_t a1 = (uint32_t)__shfl((int)pk[kk2 * 2][1],     src0, 64);
            uint32_t a2 = (uint32_t)__shfl((int)pk[kk2 * 2][0],     src1, 64);
            uint32_t a3 = (uint32_t)__shfl((int)pk[kk2 * 2][1],     src1, 64);
            uint32_t b0 = (uint32_t)__shfl((int)pk[kk2 * 2 + 1][0], src0, 64);
            uint32_t b1 = (uint32_t)__shfl((int)pk[kk2 * 2 + 1][1], src0, 64);
            uint32_t b2 = (uint32_t)__shfl((int)pk[kk2 * 2 + 1][0], src1, 64);
            uint32_t b3 = (uint32_t)__shfl((int)pk[kk2 * 2 + 1][1], src1, 64);
            union { uint32_t u[4]; short8_t v; } pf;
            pf.u[0] = hi_mt ? b0 : a0;
            pf.u[1] = hi_mt ? b1 : a1;
            pf.u[2] = hi_mt ? b2 : a2;
            pf.u[3] = hi_mt ? b3 : a3;
            __builtin_amdgcn_s_setprio(1);
#pragma unroll
            for (int dm = 0; dm < 8; dm++) {
                short8_t vf = *(const short8_t*)&Vt[(size_t)(dm * 16 + l16) * 72 + kk2 * 32 + quad * 8];
                acc[dm] = MFMA16(vf, pf.v, acc[dm]);
            }
            __builtin_amdgcn_s_setprio(0);
        }

        __syncthreads();
        if (!last) {
            STAGE_WRITE();
            __syncthreads();
        }
    }

    __hip_bfloat16* Ot = smem;
    float inv_l = 1.f / l_st;
#pragma unroll
    for (int dm = 0; dm < 8; dm++)
#pragma unroll
        for (int hh = 0; hh < 2; hh++) {
            uint32_t pv = (uint32_t)(unsigned short)f2bs(acc[dm][2 * hh] * inv_l) |
                          ((uint32_t)(unsigned short)f2bs(acc[dm][2 * hh + 1] * inv_l) << 16);
            *(uint32_t*)&Ot[(size_t)(wave * 16 + l16) * 136 + dm * 16 + quad * 4 + 2 * hh] = pv;
        }
    __syncthreads();
#pragma unroll
    for (int i = 0; i < 4; i++) {
        int c  = i * 64 + lane;
        int r2 = c >> 4, ch = c & 15;
        uint4 v = *(const uint4*)&Ot[(size_t)(wave * 16 + r2) * 136 + ch * 8];
        *(uint4*)(O + (size_t)(b * SEQ + q0 + (wave & 3) * 16 + r2) * (NH * HD) + h * HD + ch * 8) = v;
    }
#undef STAGE_LOAD
#undef STAGE_WRITE
}

// ---------------------------------------------------------------------------
extern "C" void kernel_launch(void* const* d_in, const int* in_sizes, int n_in,
                              void* d_out, int out_size, void* d_ws, size_t ws_size,
                              hipStream_t stream)
{
    const float* x  = (const float*)d_in[0];
    const float* fc = (const float*)d_in[1];
    const float* fs = (const float*)d_in[2];
    const float* wq = (const float*)d_in[3];
    const float* wk = (const float*)d_in[4];
    const float* wv = (const float*)d_in[5];
    const float* wo = (const float*)d_in[6];
    float* out = (float*)d_out;

    const int BS = 2 * SEQ;  // 4096 rows
    char* ws = (char*)d_ws;
    __hip_bfloat16* q    = (__hip_bfloat16*)(ws);
    __hip_bfloat16* k    = (__hip_bfloat16*)(ws + 33554432ull);
    __hip_bfloat16* vT   = (__hip_bfloat16*)(ws + 41943040ull);
    __hip_bfloat16* xb   = (__hip_bfloat16*)(ws + 50331648ull);
    __hip_bfloat16* attn = xb;  // alias: xb dead once projections are done
    __hip_bfloat16* wb   = (__hip_bfloat16*)(ws + 83886080ull);

    cvt_bf16<<<2048, 256, 0, stream>>>(x,  xb, (BS * 4096) / 8);
    cvt_bf16<<<2048, 256, 0, stream>>>(wq, wb, (4096 * 4096) / 8);
    gemm256<__hip_bfloat16><<<dim3(16, 16), 512, 0, stream>>>(xb, wb, q, BS, NH * HD, 4096);
    cvt_bf16<<<2048, 256, 0, stream>>>(wk, wb, (1024 * 4096) / 8);
    gemm_bt<__hip_bfloat16, false><<<dim3(8, 32), 256, 0, stream>>>(xb, wb, k, BS, NKV * HD, 4096);
    cvt_bf16<<<2048, 256, 0, stream>>>(wv, wb, (1024 * 4096) / 8);
    gemm_bt<__hip_bfloat16, true ><<<dim3(8, 32), 256, 0, stream>>>(xb, wb, vT, BS, NKV * HD, 4096);

    {
        int npq = BS * NH * 64;
        rope_kernel<<<(npq + 255) / 256, 256, 0, stream>>>(q, fc, fs, npq, 11);
        int npk = BS * NKV * 64;
        rope_kernel<<<(npk + 255) / 256, 256, 0, stream>>>(k, fc, fs, npk, 9);
    }

    flash_kernel<<<dim3(SEQ / 64, NH / 2, 2), 512, 0, stream>>>(q, k, vT, attn);

    cvt_bf16<<<2048, 256, 0, stream>>>(wo, wb, (4096 * 4096) / 8);
    gemm256<float><<<dim3(16, 16), 512, 0, stream>>>(attn, wb, out, BS, NH * HD, 4096);
}

// Round 6
// 745.303 us; speedup vs baseline: 1.6736x; 1.0818x over previous
//
#include <hip/hip_runtime.h>
#include <hip/hip_bf16.h>

typedef short short8_t __attribute__((ext_vector_type(8)));
typedef float float4_t __attribute__((ext_vector_type(4)));

#define MFMA16(A, B, C) __builtin_amdgcn_mfma_f32_16x16x32_bf16((A), (B), (C), 0, 0, 0)

#define SEQ 2048
#define HD 128
#define NH 32
#define NKV 8

__device__ inline short f2bs(float f) {
    union { __hip_bfloat16 h; short s; } u;
    u.h = __float2bfloat16(f);
    return u.s;
}

__device__ inline short8_t load8(const __hip_bfloat16* p) {
    return *(const short8_t*)p;
}
__device__ inline short8_t load8(const float* p) {
    float4_t a = *(const float4_t*)p;
    float4_t b = *(const float4_t*)(p + 4);
    short8_t r;
    r[0] = f2bs(a[0]); r[1] = f2bs(a[1]); r[2] = f2bs(a[2]); r[3] = f2bs(a[3]);
    r[4] = f2bs(b[0]); r[5] = f2bs(b[1]); r[6] = f2bs(b[2]); r[7] = f2bs(b[3]);
    return r;
}

__device__ inline void store_c(__hip_bfloat16* p, float v) { *p = __float2bfloat16(v); }
__device__ inline void store_c(float* p, float v)          { *p = v; }

// async global->LDS DMA, 16B per lane. LDS dest must be WAVE-UNIFORM base;
// hardware adds lane*16 (guide §5 caveat, m104/m108).
__device__ __forceinline__ void gld_lds16(const __hip_bfloat16* g, __hip_bfloat16* l) {
    __builtin_amdgcn_global_load_lds(
        (const __attribute__((address_space(1))) unsigned int*)g,
        (__attribute__((address_space(3))) unsigned int*)l,
        16, 0, 0);
}

// ---------------------------------------------------------------------------
// fp32 -> bf16 conversion pass (memory-bound, float4 loads, 16B/lane).
// ---------------------------------------------------------------------------
__global__ __launch_bounds__(256) void cvt_bf16(
    const float* __restrict__ in, __hip_bfloat16* __restrict__ out, int n8)
{
    int stride = gridDim.x * 256;
    for (int i = blockIdx.x * 256 + threadIdx.x; i < n8; i += stride) {
        short8_t r = load8(in + (size_t)i * 8);
        *(short8_t*)(out + (size_t)i * 8) = r;
    }
}

// ---------------------------------------------------------------------------
// Fused K+V projection: B holds wk||wv as [2048][4096] bf16.
// cols 0..1023   -> Kout[row][col]            (row-major [4096][1024])
// cols 1024..2047-> VTout[(b*1024+c2)][seq]   (V^T per batch, flash layout)
// Branch is block-uniform (128-wide tiles never straddle col 1024).
// Grid (16,32) = 512 blocks = 2/CU (vs 2x 256-block launches before).
// ---------------------------------------------------------------------------
__global__ __launch_bounds__(256) void gemm_kv(
    const __hip_bfloat16* __restrict__ A,
    const __hip_bfloat16* __restrict__ B,
    __hip_bfloat16* __restrict__ Kout,
    __hip_bfloat16* __restrict__ VTout,
    int M, int K)
{
    __shared__ __hip_bfloat16 As[128 * 32];
    __shared__ __hip_bfloat16 Bs[128 * 32];

    const int tid  = threadIdx.x;
    const int wave = tid >> 6;
    const int lane = tid & 63;
    const int quad = lane >> 4;
    const int l16  = lane & 15;
    const int m0 = blockIdx.y * 128;
    const int n0 = blockIdx.x * 128;
    const int wm = (wave >> 1) * 64;
    const int wn = (wave & 1) * 64;

    const int row0 = tid >> 2;
    const int col0 = (tid & 3) * 8;

    const __hip_bfloat16* Abase = A + (size_t)m0 * K;
    const __hip_bfloat16* Bbase = B + (size_t)n0 * K;
    __hip_bfloat16* AsW = As + wave * 512;
    __hip_bfloat16* BsW = Bs + wave * 512;

    float4_t acc[4][4] = {};

    for (int k0 = 0; k0 < K; k0 += 32) {
        __syncthreads();
        gld_lds16(Abase + (size_t)row0        * K + k0 + col0, AsW);
        gld_lds16(Abase + (size_t)(row0 + 64) * K + k0 + col0, AsW + 2048);
        gld_lds16(Bbase + (size_t)row0        * K + k0 + col0, BsW);
        gld_lds16(Bbase + (size_t)(row0 + 64) * K + k0 + col0, BsW + 2048);
        __syncthreads();

        short8_t af[4], bf[4];
#pragma unroll
        for (int t = 0; t < 4; t++)
            af[t] = *(const short8_t*)&As[(wm + t * 16 + l16) * 32 + quad * 8];
#pragma unroll
        for (int t = 0; t < 4; t++)
            bf[t] = *(const short8_t*)&Bs[(wn + t * 16 + l16) * 32 + quad * 8];
#pragma unroll
        for (int mt = 0; mt < 4; mt++)
#pragma unroll
            for (int nt = 0; nt < 4; nt++)
                acc[mt][nt] = MFMA16(af[mt], bf[nt], acc[mt][nt]);
    }

#pragma unroll
    for (int mt = 0; mt < 4; mt++)
#pragma unroll
        for (int nt = 0; nt < 4; nt++)
#pragma unroll
            for (int r = 0; r < 4; r++) {
                int row = m0 + wm + mt * 16 + quad * 4 + r;
                int col = n0 + wn + nt * 16 + l16;
                __hip_bfloat16 v = __float2bfloat16(acc[mt][nt][r]);
                if (col < 1024) {
                    Kout[(size_t)row * 1024 + col] = v;
                } else {
                    int bb = row >> 11, ss = row & (SEQ - 1);
                    VTout[((size_t)bb * 1024 + (col - 1024)) * SEQ + ss] = v;
                }
            }
}

// ---------------------------------------------------------------------------
// 256x256 8-phase GEMM (T2 swizzle + T3/T4 counted vmcnt + T5 setprio).
// Verified round 5 (806us run). See round-5 comments for the full ledger.
// ---------------------------------------------------------------------------
template <typename TC>
__global__ __launch_bounds__(512, 2) void gemm256(
    const __hip_bfloat16* __restrict__ A,
    const __hip_bfloat16* __restrict__ B,
    TC* __restrict__ C,
    int M, int N, int K)
{
    __shared__ __hip_bfloat16 lds[65536];   // 128 KiB
    __hip_bfloat16* ldsA0 = lds;
    __hip_bfloat16* ldsB0 = lds + 16384;
    __hip_bfloat16* ldsA1 = lds + 32768;
    __hip_bfloat16* ldsB1 = lds + 49152;

    const int tid  = threadIdx.x;
    const int wave = tid >> 6;
    const int lane = tid & 63;
    const int quad = lane >> 4;
    const int l16  = lane & 15;
    const int wm = wave >> 2;      // 0..1
    const int wn = wave & 3;       // 0..3
    const int m0 = blockIdx.y * 256;
    const int n0 = blockIdx.x * 256;

    const __hip_bfloat16* Abase = A + (size_t)m0 * K;
    const __hip_bfloat16* Bbase = B + (size_t)n0 * K;

    float4_t acc[8][4] = {};
    short8_t af[4][2], bf[2][2];

#define FENCE  asm volatile("" ::: "memory")
#define BAR    { FENCE; __builtin_amdgcn_s_barrier(); FENCE; }
#define LGKM0  { asm volatile("s_waitcnt lgkmcnt(0)" ::: "memory");          \
                 __builtin_amdgcn_sched_barrier(0); }
#define LGKM8  asm volatile("s_waitcnt lgkmcnt(8)" ::: "memory")
#define VM4    asm volatile("s_waitcnt vmcnt(4)" ::: "memory")
#define VM0    asm volatile("s_waitcnt vmcnt(0)" ::: "memory")

#define STAGE(GBASE, LTILE, T, H)                                            \
    {                                                                        \
        _Pragma("unroll")                                                    \
        for (int j = 0; j < 2; j++) {                                        \
            int c = j * 512 + tid;                                           \
            int r = c >> 3, s = c & 7;                                       \
            gld_lds16((GBASE) + (size_t)((H) * 128 + r) * K + (T) * 64 +     \
                          ((s ^ (r & 7)) * 8),                               \
                      (LTILE) + (H) * 8192 + j * 4096 + wave * 512);         \
        }                                                                    \
    }

#define LDA_(QM, ABASE)                                                      \
    {                                                                        \
        _Pragma("unroll")                                                    \
        for (int mt = 0; mt < 4; mt++)                                       \
            _Pragma("unroll")                                                \
            for (int kk = 0; kk < 2; kk++) {                                 \
                int row = (QM) * 128 + wm * 64 + mt * 16 + l16;              \
                int sc  = (kk * 4 + quad) ^ (row & 7);                       \
                af[mt][kk] = *(const short8_t*)&(ABASE)[row * 64 + sc * 8];  \
            }                                                                \
    }

#define LDB_(QN, BBASE)                                                      \
    {                                                                        \
        _Pragma("unroll")                                                    \
        for (int nt = 0; nt < 2; nt++)                                       \
            _Pragma("unroll")                                                \
            for (int kk = 0; kk < 2; kk++) {                                 \
                int row = (QN) * 128 + wn * 32 + nt * 16 + l16;              \
                int sc  = (kk * 4 + quad) ^ (row & 7);                       \
                bf[nt][kk] = *(const short8_t*)&(BBASE)[row * 64 + sc * 8];  \
            }                                                                \
    }

#define QMM(QM, QN)                                                          \
    __builtin_amdgcn_s_setprio(1);                                           \
    _Pragma("unroll")                                                        \
    for (int mt = 0; mt < 4; mt++)                                           \
        _Pragma("unroll")                                                    \
        for (int nt = 0; nt < 2; nt++)                                       \
            _Pragma("unroll")                                                \
            for (int kk = 0; kk < 2; kk++)                                   \
                acc[(QM) * 4 + mt][(QN) * 2 + nt] =                          \
                    MFMA16(af[mt][kk], bf[nt][kk],                           \
                           acc[(QM) * 4 + mt][(QN) * 2 + nt]);               \
    __builtin_amdgcn_s_setprio(0);

    // prologue: tile 0 complete + A1,B1 half0 of tile 1 (12 loads/thread)
    STAGE(Abase, ldsA0, 0, 0);
    STAGE(Bbase, ldsB0, 0, 0);
    STAGE(Abase, ldsA0, 0, 1);
    STAGE(Bbase, ldsB0, 0, 1);
    STAGE(Abase, ldsA1, 1, 0);
    STAGE(Bbase, ldsB1, 1, 0);
    VM4;
    BAR;

    const int NIT = (K >> 7);
#pragma unroll 1
    for (int i = 0; i < NIT - 1; i++) {
        const int T0 = 2 * i, T1 = 2 * i + 1;
        // P1
        LDA_(0, ldsA0); LDB_(0, ldsB0);
        STAGE(Bbase, ldsB1, T1, 1);
        LGKM8; BAR; LGKM0; QMM(0, 0); BAR;
        // P2
        LDB_(1, ldsB0);
        STAGE(Abase, ldsA1, T1, 1);
        BAR; LGKM0; QMM(0, 1); BAR;
        // P3
        LDA_(1, ldsA0); LDB_(0, ldsB0);
        STAGE(Abase, ldsA0, T0 + 2, 0);
        LGKM8; BAR; LGKM0; QMM(1, 0); BAR;
        // P4
        LDB_(1, ldsB0);
        STAGE(Bbase, ldsB0, T0 + 2, 0);
        VM4; BAR; LGKM0; QMM(1, 1); BAR;
        // P5
        LDA_(0, ldsA1); LDB_(0, ldsB1);
        STAGE(Bbase, ldsB0, T0 + 2, 1);
        LGKM8; BAR; LGKM0; QMM(0, 0); BAR;
        // P6
        LDB_(1, ldsB1);
        STAGE(Abase, ldsA0, T0 + 2, 1);
        BAR; LGKM0; QMM(0, 1); BAR;
        // P7
        LDA_(1, ldsA1); LDB_(0, ldsB1);
        STAGE(Abase, ldsA1, T1 + 2, 0);
        LGKM8; BAR; LGKM0; QMM(1, 0); BAR;
        // P8
        LDB_(1, ldsB1);
        STAGE(Bbase, ldsB1, T1 + 2, 0);
        VM4; BAR; LGKM0; QMM(1, 1); BAR;
    }

    // peeled final iteration
    {
        const int TL = 2 * NIT - 1;
        LDA_(0, ldsA0); LDB_(0, ldsB0);
        STAGE(Bbase, ldsB1, TL, 1);
        LGKM8; BAR; LGKM0; QMM(0, 0); BAR;
        LDB_(1, ldsB0);
        STAGE(Abase, ldsA1, TL, 1);
        BAR; LGKM0; QMM(0, 1); BAR;
        LDA_(1, ldsA0); LDB_(0, ldsB0);
        LGKM8; BAR; LGKM0; QMM(1, 0); BAR;
        LDB_(1, ldsB0);
        VM0; BAR; LGKM0; QMM(1, 1); BAR;
        LDA_(0, ldsA1); LDB_(0, ldsB1); QMM(0, 0);
        LDB_(1, ldsB1);                 QMM(0, 1);
        LDA_(1, ldsA1); LDB_(0, ldsB1); QMM(1, 0);
        LDB_(1, ldsB1);                 QMM(1, 1);
    }

#pragma unroll
    for (int qm = 0; qm < 2; qm++)
#pragma unroll
        for (int mt = 0; mt < 4; mt++)
#pragma unroll
            for (int qn = 0; qn < 2; qn++)
#pragma unroll
                for (int nt = 0; nt < 2; nt++)
#pragma unroll
                    for (int r = 0; r < 4; r++) {
                        int row = m0 + qm * 128 + wm * 64 + mt * 16 + quad * 4 + r;
                        int col = n0 + qn * 128 + wn * 32 + nt * 16 + l16;
                        store_c(&C[(size_t)row * N + col], acc[qm * 4 + mt][qn * 2 + nt][r]);
                    }
#undef STAGE
#undef LDA_
#undef LDB_
#undef QMM
#undef FENCE
#undef BAR
#undef LGKM0
#undef LGKM8
#undef VM4
#undef VM0
}

// ---------------------------------------------------------------------------
// RoPE in-place; freqs fp32 [SEQ][64].
// ---------------------------------------------------------------------------
__global__ __launch_bounds__(256) void rope_kernel(
    __hip_bfloat16* __restrict__ x,
    const float* __restrict__ cs,
    const float* __restrict__ sn,
    int npairs, int shift)
{
    int pi = blockIdx.x * 256 + threadIdx.x;
    if (pi >= npairs) return;
    int cols = 1 << shift;
    int cp   = pi & (cols - 1);
    int row  = pi >> shift;
    int d    = cp & 63;
    int pos  = row & (SEQ - 1);
    float c = cs[pos * 64 + d];
    float s = sn[pos * 64 + d];
    __hip_bfloat16* p = x + (((size_t)row) << (shift + 1)) + (size_t)cp * 2;
    float x0 = __bfloat162float(p[0]);
    float x1 = __bfloat162float(p[1]);
    p[0] = __float2bfloat16(x0 * c - x1 * s);
    p[1] = __float2bfloat16(x0 * s + x1 * c);
}

// ---------------------------------------------------------------------------
// Causal GQA flash attention, swapped-operand layout.
// Round-6 change: Ks/Vt/Ot use LINEAR rows (256B / 128B) with the XOR-16B
// bank swizzle (T2): physical_byte = row*stride + (logical ^ ((row&7)<<4)).
// Old padded layouts (Ks[][136], Vt[][72]) still serialized 8 lanes/bank on
// the MFMA-feed reads (SQ_LDS_BANK_CONFLICT 2.2e7 = ~20% of kernel time);
// the swizzle spreads 8 consecutive rows across all 32 banks (2-way = free).
// Same XOR applied on write (reg-staged, so swizzled writes are legal) and
// read; 16B granule keeps alignment (XOR touches bits 4-6 only).
// ---------------------------------------------------------------------------
__global__ __launch_bounds__(512, 4) void flash_kernel(
    const __hip_bfloat16* __restrict__ Q,
    const __hip_bfloat16* __restrict__ Km,
    const __hip_bfloat16* __restrict__ VT,
    __hip_bfloat16* __restrict__ O)
{
    // Ks 64x256B | Vt 128x128B = 32KB; epilogue reuses all 32KB as Ot 128x256B
    __shared__ __hip_bfloat16 smem[16384];
    char* KsB = (char*)smem;
    char* VtB = (char*)smem + 16384;

    const int tid  = threadIdx.x;
    const int wave = tid >> 6;
    const int lane = tid & 63;
    const int quad = lane >> 4;
    const int l16  = lane & 15;
    const int qt = ((int)blockIdx.x + (int)blockIdx.y + ((int)blockIdx.z << 4)) & 31;
    const int h  = (int)blockIdx.y * 2 + (wave >> 2);
    const int b  = blockIdx.z;
    const int kvh = blockIdx.y >> 1;
    const int q0  = qt * 64;
    const float scale = 0.08838834764831845f;
    const int qrow = q0 + (wave & 3) * 16 + l16;
    const int xk = (l16 & 7) << 4;          // per-lane row-XOR for reads

    short8_t qf[4];
    {
        const __hip_bfloat16* qp = Q + (size_t)(b * SEQ + qrow) * (NH * HD) + h * HD + quad * 8;
#pragma unroll
        for (int kk = 0; kk < 4; kk++)
            qf[kk] = *(const short8_t*)(qp + kk * 32);
    }

    float4_t acc[8] = {};
    float m_st = -1e30f, l_st = 0.f;

    const __hip_bfloat16* vbase = VT + ((size_t)(b * NKV + kvh) * HD) * SEQ;
    const __hip_bfloat16* kbase = Km + (size_t)(b * SEQ) * (NKV * HD) + kvh * HD;

    // staging indices (512 threads: K tile 64x128 = 2 uint4/thread, V same)
    const int krow0 = tid >> 4;          // 0..31
    const int kseg  = (tid & 15) * 8;    // elem offset in global K row
    const int vd0   = tid >> 3;          // 0..63
    const int vsl   = (tid & 7) * 8;     // elem offset in global V^T row
    // swizzled LDS write addresses (row&7 identical for row and row+32/64)
    const int wK0 = krow0 * 256 + ((kseg * 2) ^ ((krow0 & 7) << 4));
    const int wK1 = wK0 + 32 * 256;
    const int wV0 = vd0 * 128 + ((vsl * 2) ^ ((vd0 & 7) << 4));
    const int wV1 = wV0 + 64 * 128;

    uint4 kr0, kr1, vr0, vr1;
#define STAGE_LOAD(KT)                                                              \
    {                                                                               \
        kr0 = *(const uint4*)(kbase + (size_t)((KT) * 64 + krow0)      * (NKV * HD) + kseg); \
        kr1 = *(const uint4*)(kbase + (size_t)((KT) * 64 + krow0 + 32) * (NKV * HD) + kseg); \
        vr0 = *(const uint4*)(vbase + (size_t)vd0        * SEQ + (KT) * 64 + vsl);  \
        vr1 = *(const uint4*)(vbase + (size_t)(vd0 + 64) * SEQ + (KT) * 64 + vsl);  \
    }
#define STAGE_WRITE()                          \
    {                                          \
        *(uint4*)(KsB + wK0) = kr0;            \
        *(uint4*)(KsB + wK1) = kr1;            \
        *(uint4*)(VtB + wV0) = vr0;            \
        *(uint4*)(VtB + wV1) = vr1;            \
    }

    STAGE_LOAD(0);
    STAGE_WRITE();
    __syncthreads();

    for (int kt = 0; kt <= qt; kt++) {
        const bool last = (kt == qt);
        if (!last) STAGE_LOAD(kt + 1);

        float4_t st[4] = {};
        __builtin_amdgcn_s_setprio(1);
#pragma unroll
        for (int kk = 0; kk < 4; kk++)
#pragma unroll
            for (int mt = 0; mt < 4; mt++) {
                short8_t kf = *(const short8_t*)(KsB + (mt * 16 + l16) * 256 +
                                                 ((kk * 64 + quad * 16) ^ xk));
                st[mt] = MFMA16(kf, qf[kk], st[mt]);
            }
        __builtin_amdgcn_s_setprio(0);

        float mx = -1e30f;
        if (last) {
#pragma unroll
            for (int mt = 0; mt < 4; mt++)
#pragma unroll
                for (int r = 0; r < 4; r++) {
                    int key = kt * 64 + mt * 16 + quad * 4 + r;
                    float s = st[mt][r] * scale;
                    if (key > qrow) s = -1e30f;
                    st[mt][r] = s;
                    mx = fmaxf(mx, s);
                }
        } else {
#pragma unroll
            for (int mt = 0; mt < 4; mt++)
#pragma unroll
                for (int r = 0; r < 4; r++) {
                    float s = st[mt][r] * scale;
                    st[mt][r] = s;
                    mx = fmaxf(mx, s);
                }
        }
        mx = fmaxf(mx, __shfl_xor(mx, 16, 64));
        mx = fmaxf(mx, __shfl_xor(mx, 32, 64));

        float mcur;
        if (__all(mx <= m_st + 8.f)) {
            mcur = m_st;
        } else {
            float mnew  = fmaxf(m_st, mx);
            float alpha = __expf(m_st - mnew);
            l_st *= alpha;
#pragma unroll
            for (int dm = 0; dm < 8; dm++)
                acc[dm] *= alpha;
            m_st = mnew;
            mcur = mnew;
        }

        uint32_t pk[4][2];
        float rsum = 0.f;
#pragma unroll
        for (int mt = 0; mt < 4; mt++)
#pragma unroll
            for (int hh = 0; hh < 2; hh++) {
                float p0 = __expf(st[mt][2 * hh]     - mcur);
                float p1 = __expf(st[mt][2 * hh + 1] - mcur);
                rsum += p0 + p1;
                pk[mt][hh] = (uint32_t)(unsigned short)f2bs(p0) |
                             ((uint32_t)(unsigned short)f2bs(p1) << 16);
            }
        rsum += __shfl_xor(rsum, 16, 64);
        rsum += __shfl_xor(rsum, 32, 64);
        l_st += rsum;

        const int src0 = ((quad & 1) * 2) * 16 + l16;
        const int src1 = src0 + 16;
        const bool hi_mt = (quad >> 1) != 0;
#pragma unroll
        for (int kk2 = 0; kk2 < 2; kk2++) {
            uint32_t a0 = (uint32_t)__shfl((int)pk[kk2 * 2][0],     src0, 64);
            uint32_t a1 = (uint32_t)__shfl((int)pk[kk2 * 2][1],     src0, 64);
            uint32_t a2 = (uint32_t)__shfl((int)pk[kk2 * 2][0],     src1, 64);
            uint32_t a3 = (uint32_t)__shfl((int)pk[kk2 * 2][1],     src1, 64);
            uint32_t b0 = (uint32_t)__shfl((int)pk[kk2 * 2 + 1][0], src0, 64);
            uint32_t b1 = (uint32_t)__shfl((int)pk[kk2 * 2 + 1][1], src0, 64);
            uint32_t b2 = (uint32_t)__shfl((int)pk[kk2 * 2 + 1][0], src1, 64);
            uint32_t b3 = (uint32_t)__shfl((int)pk[kk2 * 2 + 1][1], src1, 64);
            union { uint32_t u[4]; short8_t v; } pf;
            pf.u[0] = hi_mt ? b0 : a0;
            pf.u[1] = hi_mt ? b1 : a1;
            pf.u[2] = hi_mt ? b2 : a2;
            pf.u[3] = hi_mt ? b3 : a3;
            __builtin_amdgcn_s_setprio(1);
#pragma unroll
            for (int dm = 0; dm < 8; dm++) {
                short8_t vf = *(const short8_t*)(VtB + (dm * 16 + l16) * 128 +
                                                 ((kk2 * 64 + quad * 16) ^ xk));
                acc[dm] = MFMA16(vf, pf.v, acc[dm]);
            }
            __builtin_amdgcn_s_setprio(0);
        }

        __syncthreads();
        if (!last) {
            STAGE_WRITE();
            __syncthreads();
        }
    }

    // epilogue: O^T -> O via LDS transpose; Ot = 128 rows x 256B, same swizzle
    char* OtB = (char*)smem;
    float inv_l = 1.f / l_st;
#pragma unroll
    for (int dm = 0; dm < 8; dm++)
#pragma unroll
        for (int hh = 0; hh < 2; hh++) {
            uint32_t pv = (uint32_t)(unsigned short)f2bs(acc[dm][2 * hh] * inv_l) |
                          ((uint32_t)(unsigned short)f2bs(acc[dm][2 * hh + 1] * inv_l) << 16);
            *(uint32_t*)(OtB + (wave * 16 + l16) * 256 +
                         ((dm * 32 + quad * 8 + 4 * hh) ^ xk)) = pv;
        }
    __syncthreads();
#pragma unroll
    for (int i = 0; i < 4; i++) {
        int c  = i * 64 + lane;
        int r2 = c >> 4, ch = c & 15;
        uint4 v = *(const uint4*)(OtB + (wave * 16 + r2) * 256 +
                                  ((ch * 16) ^ ((r2 & 7) << 4)));
        *(uint4*)(O + (size_t)(b * SEQ + q0 + (wave & 3) * 16 + r2) * (NH * HD) + h * HD + ch * 8) = v;
    }
#undef STAGE_LOAD
#undef STAGE_WRITE
}

// ---------------------------------------------------------------------------
extern "C" void kernel_launch(void* const* d_in, const int* in_sizes, int n_in,
                              void* d_out, int out_size, void* d_ws, size_t ws_size,
                              hipStream_t stream)
{
    const float* x  = (const float*)d_in[0];
    const float* fc = (const float*)d_in[1];
    const float* fs = (const float*)d_in[2];
    const float* wq = (const float*)d_in[3];
    const float* wk = (const float*)d_in[4];
    const float* wv = (const float*)d_in[5];
    const float* wo = (const float*)d_in[6];
    float* out = (float*)d_out;

    const int BS = 2 * SEQ;  // 4096 rows
    char* ws = (char*)d_ws;
    // workspace layout (112 MB):
    //   [0,32M)    q     4096x4096 bf16
    //   [32,40M)   k     4096x1024 bf16
    //   [40,48M)   vT    [b][kvh][d][2048] bf16
    //   [48,80M)   xb (x in bf16)  -- aliased with attn (xb dead before flash)
    //   [80,112M)  wb    shared converted-weight slot (wq / wk||wv / wo)
    __hip_bfloat16* q    = (__hip_bfloat16*)(ws);
    __hip_bfloat16* k    = (__hip_bfloat16*)(ws + 33554432ull);
    __hip_bfloat16* vT   = (__hip_bfloat16*)(ws + 41943040ull);
    __hip_bfloat16* xb   = (__hip_bfloat16*)(ws + 50331648ull);
    __hip_bfloat16* attn = xb;  // alias: xb dead once projections are done
    __hip_bfloat16* wb   = (__hip_bfloat16*)(ws + 83886080ull);

    cvt_bf16<<<2048, 256, 0, stream>>>(x,  xb, (BS * 4096) / 8);
    cvt_bf16<<<2048, 256, 0, stream>>>(wq, wb, (4096 * 4096) / 8);
    gemm256<__hip_bfloat16><<<dim3(16, 16), 512, 0, stream>>>(xb, wb, q, BS, NH * HD, 4096);

    // fused K+V projection: wb = wk || wv as [2048][4096]
    cvt_bf16<<<2048, 256, 0, stream>>>(wk, wb,                 (1024 * 4096) / 8);
    cvt_bf16<<<2048, 256, 0, stream>>>(wv, wb + 4194304ull,    (1024 * 4096) / 8);
    gemm_kv<<<dim3(16, 32), 256, 0, stream>>>(xb, wb, k, vT, BS, 4096);

    {
        int npq = BS * NH * 64;
        rope_kernel<<<(npq + 255) / 256, 256, 0, stream>>>(q, fc, fs, npq, 11);
        int npk = BS * NKV * 64;
        rope_kernel<<<(npk + 255) / 256, 256, 0, stream>>>(k, fc, fs, npk, 9);
    }

    flash_kernel<<<dim3(SEQ / 64, NH / 2, 2), 512, 0, stream>>>(q, k, vT, attn);

    cvt_bf16<<<2048, 256, 0, stream>>>(wo, wb, (4096 * 4096) / 8);
    gemm256<float><<<dim3(16, 16), 512, 0, stream>>>(attn, wb, out, BS, NH * HD, 4096);
}

// Round 7
// 733.386 us; speedup vs baseline: 1.7008x; 1.0162x over previous
//
#include <hip/hip_runtime.h>
#include <hip/hip_bf16.h>

typedef short short8_t __attribute__((ext_vector_type(8)));
typedef float float4_t __attribute__((ext_vector_type(4)));

#define MFMA16(A, B, C) __builtin_amdgcn_mfma_f32_16x16x32_bf16((A), (B), (C), 0, 0, 0)

#define SEQ 2048
#define HD 128
#define NH 32
#define NKV 8

__device__ inline short f2bs(float f) {
    union { __hip_bfloat16 h; short s; } u;
    u.h = __float2bfloat16(f);
    return u.s;
}

__device__ inline short8_t load8(const __hip_bfloat16* p) {
    return *(const short8_t*)p;
}
__device__ inline short8_t load8(const float* p) {
    float4_t a = *(const float4_t*)p;
    float4_t b = *(const float4_t*)(p + 4);
    short8_t r;
    r[0] = f2bs(a[0]); r[1] = f2bs(a[1]); r[2] = f2bs(a[2]); r[3] = f2bs(a[3]);
    r[4] = f2bs(b[0]); r[5] = f2bs(b[1]); r[6] = f2bs(b[2]); r[7] = f2bs(b[3]);
    return r;
}

__device__ inline void store_c(__hip_bfloat16* p, float v) { *p = __float2bfloat16(v); }
__device__ inline void store_c(float* p, float v)          { *p = v; }

// async global->LDS DMA, 16B per lane. LDS dest must be WAVE-UNIFORM base;
// hardware adds lane*16 (guide §5 caveat, m104/m108).
__device__ __forceinline__ void gld_lds16(const __hip_bfloat16* g, __hip_bfloat16* l) {
    __builtin_amdgcn_global_load_lds(
        (const __attribute__((address_space(1))) unsigned int*)g,
        (__attribute__((address_space(3))) unsigned int*)l,
        16, 0, 0);
}

// ---------------------------------------------------------------------------
// fp32 -> bf16 conversion pass (memory-bound, float4 loads, 16B/lane).
// ---------------------------------------------------------------------------
__global__ __launch_bounds__(256) void cvt_bf16(
    const float* __restrict__ in, __hip_bfloat16* __restrict__ out, int n8)
{
    int stride = gridDim.x * 256;
    for (int i = blockIdx.x * 256 + threadIdx.x; i < n8; i += stride) {
        short8_t r = load8(in + (size_t)i * 8);
        *(short8_t*)(out + (size_t)i * 8) = r;
    }
}

// ---------------------------------------------------------------------------
// Fused K+V projection: B holds wk||wv as [2048][4096] bf16.
// cols 0..1023   -> Kout[row][col]; cols 1024..2047 -> VTout (V^T per batch).
// ---------------------------------------------------------------------------
__global__ __launch_bounds__(256) void gemm_kv(
    const __hip_bfloat16* __restrict__ A,
    const __hip_bfloat16* __restrict__ B,
    __hip_bfloat16* __restrict__ Kout,
    __hip_bfloat16* __restrict__ VTout,
    int M, int K)
{
    __shared__ __hip_bfloat16 As[128 * 32];
    __shared__ __hip_bfloat16 Bs[128 * 32];

    const int tid  = threadIdx.x;
    const int wave = tid >> 6;
    const int lane = tid & 63;
    const int quad = lane >> 4;
    const int l16  = lane & 15;
    const int m0 = blockIdx.y * 128;
    const int n0 = blockIdx.x * 128;
    const int wm = (wave >> 1) * 64;
    const int wn = (wave & 1) * 64;

    const int row0 = tid >> 2;
    const int col0 = (tid & 3) * 8;

    const __hip_bfloat16* Abase = A + (size_t)m0 * K;
    const __hip_bfloat16* Bbase = B + (size_t)n0 * K;
    __hip_bfloat16* AsW = As + wave * 512;
    __hip_bfloat16* BsW = Bs + wave * 512;

    float4_t acc[4][4] = {};

    for (int k0 = 0; k0 < K; k0 += 32) {
        __syncthreads();
        gld_lds16(Abase + (size_t)row0        * K + k0 + col0, AsW);
        gld_lds16(Abase + (size_t)(row0 + 64) * K + k0 + col0, AsW + 2048);
        gld_lds16(Bbase + (size_t)row0        * K + k0 + col0, BsW);
        gld_lds16(Bbase + (size_t)(row0 + 64) * K + k0 + col0, BsW + 2048);
        __syncthreads();

        short8_t af[4], bf[4];
#pragma unroll
        for (int t = 0; t < 4; t++)
            af[t] = *(const short8_t*)&As[(wm + t * 16 + l16) * 32 + quad * 8];
#pragma unroll
        for (int t = 0; t < 4; t++)
            bf[t] = *(const short8_t*)&Bs[(wn + t * 16 + l16) * 32 + quad * 8];
#pragma unroll
        for (int mt = 0; mt < 4; mt++)
#pragma unroll
            for (int nt = 0; nt < 4; nt++)
                acc[mt][nt] = MFMA16(af[mt], bf[nt], acc[mt][nt]);
    }

#pragma unroll
    for (int mt = 0; mt < 4; mt++)
#pragma unroll
        for (int nt = 0; nt < 4; nt++)
#pragma unroll
            for (int r = 0; r < 4; r++) {
                int row = m0 + wm + mt * 16 + quad * 4 + r;
                int col = n0 + wn + nt * 16 + l16;
                __hip_bfloat16 v = __float2bfloat16(acc[mt][nt][r]);
                if (col < 1024) {
                    Kout[(size_t)row * 1024 + col] = v;
                } else {
                    int bb = row >> 11, ss = row & (SEQ - 1);
                    VTout[((size_t)bb * 1024 + (col - 1024)) * SEQ + ss] = v;
                }
            }
}

// ---------------------------------------------------------------------------
// 256x256 8-phase GEMM (T2 swizzle + T3/T4 counted vmcnt + T5 setprio).
// Verified rounds 5-6. See round-5 comments for the full hazard ledger.
// ---------------------------------------------------------------------------
template <typename TC>
__global__ __launch_bounds__(512, 2) void gemm256(
    const __hip_bfloat16* __restrict__ A,
    const __hip_bfloat16* __restrict__ B,
    TC* __restrict__ C,
    int M, int N, int K)
{
    __shared__ __hip_bfloat16 lds[65536];   // 128 KiB
    __hip_bfloat16* ldsA0 = lds;
    __hip_bfloat16* ldsB0 = lds + 16384;
    __hip_bfloat16* ldsA1 = lds + 32768;
    __hip_bfloat16* ldsB1 = lds + 49152;

    const int tid  = threadIdx.x;
    const int wave = tid >> 6;
    const int lane = tid & 63;
    const int quad = lane >> 4;
    const int l16  = lane & 15;
    const int wm = wave >> 2;      // 0..1
    const int wn = wave & 3;       // 0..3
    const int m0 = blockIdx.y * 256;
    const int n0 = blockIdx.x * 256;

    const __hip_bfloat16* Abase = A + (size_t)m0 * K;
    const __hip_bfloat16* Bbase = B + (size_t)n0 * K;

    float4_t acc[8][4] = {};
    short8_t af[4][2], bf[2][2];

#define FENCE  asm volatile("" ::: "memory")
#define BAR    { FENCE; __builtin_amdgcn_s_barrier(); FENCE; }
#define LGKM0  { asm volatile("s_waitcnt lgkmcnt(0)" ::: "memory");          \
                 __builtin_amdgcn_sched_barrier(0); }
#define LGKM8  asm volatile("s_waitcnt lgkmcnt(8)" ::: "memory")
#define VM4    asm volatile("s_waitcnt vmcnt(4)" ::: "memory")
#define VM0    asm volatile("s_waitcnt vmcnt(0)" ::: "memory")

#define STAGE(GBASE, LTILE, T, H)                                            \
    {                                                                        \
        _Pragma("unroll")                                                    \
        for (int j = 0; j < 2; j++) {                                        \
            int c = j * 512 + tid;                                           \
            int r = c >> 3, s = c & 7;                                       \
            gld_lds16((GBASE) + (size_t)((H) * 128 + r) * K + (T) * 64 +     \
                          ((s ^ (r & 7)) * 8),                               \
                      (LTILE) + (H) * 8192 + j * 4096 + wave * 512);         \
        }                                                                    \
    }

#define LDA_(QM, ABASE)                                                      \
    {                                                                        \
        _Pragma("unroll")                                                    \
        for (int mt = 0; mt < 4; mt++)                                       \
            _Pragma("unroll")                                                \
            for (int kk = 0; kk < 2; kk++) {                                 \
                int row = (QM) * 128 + wm * 64 + mt * 16 + l16;              \
                int sc  = (kk * 4 + quad) ^ (row & 7);                       \
                af[mt][kk] = *(const short8_t*)&(ABASE)[row * 64 + sc * 8];  \
            }                                                                \
    }

#define LDB_(QN, BBASE)                                                      \
    {                                                                        \
        _Pragma("unroll")                                                    \
        for (int nt = 0; nt < 2; nt++)                                       \
            _Pragma("unroll")                                                \
            for (int kk = 0; kk < 2; kk++) {                                 \
                int row = (QN) * 128 + wn * 32 + nt * 16 + l16;              \
                int sc  = (kk * 4 + quad) ^ (row & 7);                       \
                bf[nt][kk] = *(const short8_t*)&(BBASE)[row * 64 + sc * 8];  \
            }                                                                \
    }

#define QMM(QM, QN)                                                          \
    __builtin_amdgcn_s_setprio(1);                                           \
    _Pragma("unroll")                                                        \
    for (int mt = 0; mt < 4; mt++)                                           \
        _Pragma("unroll")                                                    \
        for (int nt = 0; nt < 2; nt++)                                       \
            _Pragma("unroll")                                                \
            for (int kk = 0; kk < 2; kk++)                                   \
                acc[(QM) * 4 + mt][(QN) * 2 + nt] =                          \
                    MFMA16(af[mt][kk], bf[nt][kk],                           \
                           acc[(QM) * 4 + mt][(QN) * 2 + nt]);               \
    __builtin_amdgcn_s_setprio(0);

    // prologue: tile 0 complete + A1,B1 half0 of tile 1 (12 loads/thread)
    STAGE(Abase, ldsA0, 0, 0);
    STAGE(Bbase, ldsB0, 0, 0);
    STAGE(Abase, ldsA0, 0, 1);
    STAGE(Bbase, ldsB0, 0, 1);
    STAGE(Abase, ldsA1, 1, 0);
    STAGE(Bbase, ldsB1, 1, 0);
    VM4;
    BAR;

    const int NIT = (K >> 7);
#pragma unroll 1
    for (int i = 0; i < NIT - 1; i++) {
        const int T0 = 2 * i, T1 = 2 * i + 1;
        // P1
        LDA_(0, ldsA0); LDB_(0, ldsB0);
        STAGE(Bbase, ldsB1, T1, 1);
        LGKM8; BAR; LGKM0; QMM(0, 0); BAR;
        // P2
        LDB_(1, ldsB0);
        STAGE(Abase, ldsA1, T1, 1);
        BAR; LGKM0; QMM(0, 1); BAR;
        // P3
        LDA_(1, ldsA0); LDB_(0, ldsB0);
        STAGE(Abase, ldsA0, T0 + 2, 0);
        LGKM8; BAR; LGKM0; QMM(1, 0); BAR;
        // P4
        LDB_(1, ldsB0);
        STAGE(Bbase, ldsB0, T0 + 2, 0);
        VM4; BAR; LGKM0; QMM(1, 1); BAR;
        // P5
        LDA_(0, ldsA1); LDB_(0, ldsB1);
        STAGE(Bbase, ldsB0, T0 + 2, 1);
        LGKM8; BAR; LGKM0; QMM(0, 0); BAR;
        // P6
        LDB_(1, ldsB1);
        STAGE(Abase, ldsA0, T0 + 2, 1);
        BAR; LGKM0; QMM(0, 1); BAR;
        // P7
        LDA_(1, ldsA1); LDB_(0, ldsB1);
        STAGE(Abase, ldsA1, T1 + 2, 0);
        LGKM8; BAR; LGKM0; QMM(1, 0); BAR;
        // P8
        LDB_(1, ldsB1);
        STAGE(Bbase, ldsB1, T1 + 2, 0);
        VM4; BAR; LGKM0; QMM(1, 1); BAR;
    }

    // peeled final iteration
    {
        const int TL = 2 * NIT - 1;
        LDA_(0, ldsA0); LDB_(0, ldsB0);
        STAGE(Bbase, ldsB1, TL, 1);
        LGKM8; BAR; LGKM0; QMM(0, 0); BAR;
        LDB_(1, ldsB0);
        STAGE(Abase, ldsA1, TL, 1);
        BAR; LGKM0; QMM(0, 1); BAR;
        LDA_(1, ldsA0); LDB_(0, ldsB0);
        LGKM8; BAR; LGKM0; QMM(1, 0); BAR;
        LDB_(1, ldsB0);
        VM0; BAR; LGKM0; QMM(1, 1); BAR;
        LDA_(0, ldsA1); LDB_(0, ldsB1); QMM(0, 0);
        LDB_(1, ldsB1);                 QMM(0, 1);
        LDA_(1, ldsA1); LDB_(0, ldsB1); QMM(1, 0);
        LDB_(1, ldsB1);                 QMM(1, 1);
    }

#pragma unroll
    for (int qm = 0; qm < 2; qm++)
#pragma unroll
        for (int mt = 0; mt < 4; mt++)
#pragma unroll
            for (int qn = 0; qn < 2; qn++)
#pragma unroll
                for (int nt = 0; nt < 2; nt++)
#pragma unroll
                    for (int r = 0; r < 4; r++) {
                        int row = m0 + qm * 128 + wm * 64 + mt * 16 + quad * 4 + r;
                        int col = n0 + qn * 128 + wn * 32 + nt * 16 + l16;
                        store_c(&C[(size_t)row * N + col], acc[qm * 4 + mt][qn * 2 + nt][r]);
                    }
#undef STAGE
#undef LDA_
#undef LDB_
#undef QMM
#undef FENCE
#undef BAR
#undef LGKM0
#undef LGKM8
#undef VM4
#undef VM0
}

// ---------------------------------------------------------------------------
// RoPE in-place; freqs fp32 [SEQ][64].
// ---------------------------------------------------------------------------
__global__ __launch_bounds__(256) void rope_kernel(
    __hip_bfloat16* __restrict__ x,
    const float* __restrict__ cs,
    const float* __restrict__ sn,
    int npairs, int shift)
{
    int pi = blockIdx.x * 256 + threadIdx.x;
    if (pi >= npairs) return;
    int cols = 1 << shift;
    int cp   = pi & (cols - 1);
    int row  = pi >> shift;
    int d    = cp & 63;
    int pos  = row & (SEQ - 1);
    float c = cs[pos * 64 + d];
    float s = sn[pos * 64 + d];
    __hip_bfloat16* p = x + (((size_t)row) << (shift + 1)) + (size_t)cp * 2;
    float x0 = __bfloat162float(p[0]);
    float x1 = __bfloat162float(p[1]);
    p[0] = __float2bfloat16(x0 * c - x1 * s);
    p[1] = __float2bfloat16(x0 * s + x1 * c);
}

// ---------------------------------------------------------------------------
// Causal GQA flash attention, swapped-operand layout. Round-7 structure:
// - Triangle pairing: block x=p owns q-tiles {p, 31-p} of head y: EVERY block
//   does exactly 33 tile-computes -> perfect balance (replaces qt stagger).
//   Waves 0-3: tile p rows; waves 4-7: tile 31-p rows. `kt<=myqt` wave-uniform.
// - K/V double-buffered in LDS (64KB) via global_load_lds: linear dest +
//   inverse-XOR source (rule #21); reads keep round-6 swizzle (row&7==l16&7).
// - ONE barrier per iter: __syncthreads' vmcnt(0) drain retires DMA(kt)
//   (issued a full iteration earlier -> latency hidden); then issue DMA(kt+1)
//   into the buffer freed by the barrier.
// ---------------------------------------------------------------------------
__global__ __launch_bounds__(512, 4) void flash_kernel(
    const __hip_bfloat16* __restrict__ Q,
    const __hip_bfloat16* __restrict__ Km,
    const __hip_bfloat16* __restrict__ VT,
    __hip_bfloat16* __restrict__ O)
{
    // 64KB: buf b at b*32KB = [K 64x256B | V 128x128B]; epilogue reuses 32KB.
    __shared__ __hip_bfloat16 smem[32768];

    const int tid  = threadIdx.x;
    const int wave = tid >> 6;
    const int lane = tid & 63;
    const int quad = lane >> 4;
    const int l16  = lane & 15;
    const int p   = blockIdx.x;            // 0..15
    const int h   = blockIdx.y;
    const int b   = blockIdx.z;
    const int kvh = h >> 2;
    const int qtB = 31 - p;
    const int myqt = (wave >> 2) ? qtB : p;
    const int q0   = myqt * 64;
    const float scale = 0.08838834764831845f;
    const int qrow = q0 + (wave & 3) * 16 + l16;
    const int xk = (l16 & 7) << 4;         // row-XOR for swizzled reads

    short8_t qf[4];
    {
        const __hip_bfloat16* qp = Q + (size_t)(b * SEQ + qrow) * (NH * HD) + h * HD + quad * 8;
#pragma unroll
        for (int kk = 0; kk < 4; kk++)
            qf[kk] = *(const short8_t*)(qp + kk * 32);
    }

    float4_t acc[8] = {};
    float m_st = -1e30f, l_st = 0.f;

    const __hip_bfloat16* vbase = VT + ((size_t)(b * NKV + kvh) * HD) * SEQ;
    const __hip_bfloat16* kbase = Km + (size_t)(b * SEQ) * (NKV * HD) + kvh * HD;

    // DMA one K/V tile into buf (kt&1). K: 64 rows x 16 chunks; V: 128 x 8.
    // Stored chunk s of row r holds global chunk s^(r&7) (inverse of read XOR).
    auto stage = [&](int kt) {
        __hip_bfloat16* Kb = smem + (size_t)(kt & 1) * 16384;
        __hip_bfloat16* Vb = Kb + 8192;
#pragma unroll
        for (int j = 0; j < 2; j++) {
            int c = j * 512 + tid;
            int kr = c >> 4, ks = c & 15;
            gld_lds16(kbase + (size_t)(kt * 64 + kr) * (NKV * HD) + ((ks ^ (kr & 7)) * 8),
                      Kb + j * 4096 + wave * 512);
            int vd = c >> 3, vs = c & 7;
            gld_lds16(vbase + (size_t)vd * SEQ + kt * 64 + ((vs ^ (vd & 7)) * 8),
                      Vb + j * 4096 + wave * 512);
        }
    };

    stage(0);

    for (int kt = 0; kt <= qtB; kt++) {
        asm volatile("s_waitcnt vmcnt(0)" ::: "memory");  // DMA(kt) landed
        __syncthreads();          // + all waves done reading buf[(kt+1)&1]
        if (kt < qtB) stage(kt + 1);

        if (kt <= myqt) {         // wave-uniform
            const char* Kb = (const char*)(smem + (size_t)(kt & 1) * 16384);
            const char* Vb = Kb + 16384;
            const bool diag = (kt == myqt);

            float4_t st[4] = {};
            __builtin_amdgcn_s_setprio(1);
#pragma unroll
            for (int kk = 0; kk < 4; kk++)
#pragma unroll
                for (int mt = 0; mt < 4; mt++) {
                    short8_t kf = *(const short8_t*)(Kb + (mt * 16 + l16) * 256 +
                                                     ((kk * 64 + quad * 16) ^ xk));
                    st[mt] = MFMA16(kf, qf[kk], st[mt]);
                }
            __builtin_amdgcn_s_setprio(0);

            float mx = -1e30f;
            if (diag) {
#pragma unroll
                for (int mt = 0; mt < 4; mt++)
#pragma unroll
                    for (int r = 0; r < 4; r++) {
                        int key = kt * 64 + mt * 16 + quad * 4 + r;
                        float s = st[mt][r] * scale;
                        if (key > qrow) s = -1e30f;
                        st[mt][r] = s;
                        mx = fmaxf(mx, s);
                    }
            } else {
#pragma unroll
                for (int mt = 0; mt < 4; mt++)
#pragma unroll
                    for (int r = 0; r < 4; r++) {
                        float s = st[mt][r] * scale;
                        st[mt][r] = s;
                        mx = fmaxf(mx, s);
                    }
            }
            mx = fmaxf(mx, __shfl_xor(mx, 16, 64));
            mx = fmaxf(mx, __shfl_xor(mx, 32, 64));

            float mcur;
            if (__all(mx <= m_st + 8.f)) {
                mcur = m_st;
            } else {
                float mnew  = fmaxf(m_st, mx);
                float alpha = __expf(m_st - mnew);
                l_st *= alpha;
#pragma unroll
                for (int dm = 0; dm < 8; dm++)
                    acc[dm] *= alpha;
                m_st = mnew;
                mcur = mnew;
            }

            uint32_t pk[4][2];
            float rsum = 0.f;
#pragma unroll
            for (int mt = 0; mt < 4; mt++)
#pragma unroll
                for (int hh = 0; hh < 2; hh++) {
                    float p0 = __expf(st[mt][2 * hh]     - mcur);
                    float p1 = __expf(st[mt][2 * hh + 1] - mcur);
                    rsum += p0 + p1;
                    pk[mt][hh] = (uint32_t)(unsigned short)f2bs(p0) |
                                 ((uint32_t)(unsigned short)f2bs(p1) << 16);
                }
            rsum += __shfl_xor(rsum, 16, 64);
            rsum += __shfl_xor(rsum, 32, 64);
            l_st += rsum;

            const int src0 = ((quad & 1) * 2) * 16 + l16;
            const int src1 = src0 + 16;
            const bool hi_mt = (quad >> 1) != 0;
#pragma unroll
            for (int kk2 = 0; kk2 < 2; kk2++) {
                uint32_t a0 = (uint32_t)__shfl((int)pk[kk2 * 2][0],     src0, 64);
                uint32_t a1 = (uint32_t)__shfl((int)pk[kk2 * 2][1],     src0, 64);
                uint32_t a2 = (uint32_t)__shfl((int)pk[kk2 * 2][0],     src1, 64);
                uint32_t a3 = (uint32_t)__shfl((int)pk[kk2 * 2][1],     src1, 64);
                uint32_t b0 = (uint32_t)__shfl((int)pk[kk2 * 2 + 1][0], src0, 64);
                uint32_t b1 = (uint32_t)__shfl((int)pk[kk2 * 2 + 1][1], src0, 64);
                uint32_t b2 = (uint32_t)__shfl((int)pk[kk2 * 2 + 1][0], src1, 64);
                uint32_t b3 = (uint32_t)__shfl((int)pk[kk2 * 2 + 1][1], src1, 64);
                union { uint32_t u[4]; short8_t v; } pf;
                pf.u[0] = hi_mt ? b0 : a0;
                pf.u[1] = hi_mt ? b1 : a1;
                pf.u[2] = hi_mt ? b2 : a2;
                pf.u[3] = hi_mt ? b3 : a3;
                __builtin_amdgcn_s_setprio(1);
#pragma unroll
                for (int dm = 0; dm < 8; dm++) {
                    short8_t vf = *(const short8_t*)(Vb + (dm * 16 + l16) * 128 +
                                                     ((kk2 * 64 + quad * 16) ^ xk));
                    acc[dm] = MFMA16(vf, pf.v, acc[dm]);
                }
                __builtin_amdgcn_s_setprio(0);
            }
        }
    }

    // epilogue: O^T -> O via LDS transpose; Ot = 128 rows x 256B (32KB).
    // Each wave's 16 rows are written and read only by itself; barriers
    // guard the alias with the K/V buffers.
    __syncthreads();
    char* OtB = (char*)smem;
    float inv_l = 1.f / l_st;
#pragma unroll
    for (int dm = 0; dm < 8; dm++)
#pragma unroll
        for (int hh = 0; hh < 2; hh++) {
            uint32_t pv = (uint32_t)(unsigned short)f2bs(acc[dm][2 * hh] * inv_l) |
                          ((uint32_t)(unsigned short)f2bs(acc[dm][2 * hh + 1] * inv_l) << 16);
            *(uint32_t*)(OtB + (wave * 16 + l16) * 256 +
                         ((dm * 32 + quad * 8 + 4 * hh) ^ xk)) = pv;
        }
    __syncthreads();
#pragma unroll
    for (int i = 0; i < 4; i++) {
        int c  = i * 64 + lane;
        int r2 = c >> 4, ch = c & 15;
        uint4 v = *(const uint4*)(OtB + (wave * 16 + r2) * 256 +
                                  ((ch * 16) ^ ((r2 & 7) << 4)));
        *(uint4*)(O + (size_t)(b * SEQ + q0 + (wave & 3) * 16 + r2) * (NH * HD) + h * HD + ch * 8) = v;
    }
}

// ---------------------------------------------------------------------------
extern "C" void kernel_launch(void* const* d_in, const int* in_sizes, int n_in,
                              void* d_out, int out_size, void* d_ws, size_t ws_size,
                              hipStream_t stream)
{
    const float* x  = (const float*)d_in[0];
    const float* fc = (const float*)d_in[1];
    const float* fs = (const float*)d_in[2];
    const float* wq = (const float*)d_in[3];
    const float* wk = (const float*)d_in[4];
    const float* wv = (const float*)d_in[5];
    const float* wo = (const float*)d_in[6];
    float* out = (float*)d_out;

    const int BS = 2 * SEQ;  // 4096 rows
    char* ws = (char*)d_ws;
    // workspace layout (112 MB):
    //   [0,32M)    q     4096x4096 bf16
    //   [32,40M)   k     4096x1024 bf16
    //   [40,48M)   vT    [b][kvh][d][2048] bf16
    //   [48,80M)   xb (x in bf16)  -- aliased with attn (xb dead before flash)
    //   [80,112M)  wb    shared converted-weight slot (wq / wk||wv / wo)
    __hip_bfloat16* q    = (__hip_bfloat16*)(ws);
    __hip_bfloat16* k    = (__hip_bfloat16*)(ws + 33554432ull);
    __hip_bfloat16* vT   = (__hip_bfloat16*)(ws + 41943040ull);
    __hip_bfloat16* xb   = (__hip_bfloat16*)(ws + 50331648ull);
    __hip_bfloat16* attn = xb;  // alias: xb dead once projections are done
    __hip_bfloat16* wb   = (__hip_bfloat16*)(ws + 83886080ull);

    cvt_bf16<<<2048, 256, 0, stream>>>(x,  xb, (BS * 4096) / 8);
    cvt_bf16<<<2048, 256, 0, stream>>>(wq, wb, (4096 * 4096) / 8);
    gemm256<__hip_bfloat16><<<dim3(16, 16), 512, 0, stream>>>(xb, wb, q, BS, NH * HD, 4096);

    // fused K+V projection: wb = wk || wv as [2048][4096]
    cvt_bf16<<<2048, 256, 0, stream>>>(wk, wb,              (1024 * 4096) / 8);
    cvt_bf16<<<2048, 256, 0, stream>>>(wv, wb + 4194304ull, (1024 * 4096) / 8);
    gemm_kv<<<dim3(16, 32), 256, 0, stream>>>(xb, wb, k, vT, BS, 4096);

    {
        int npq = BS * NH * 64;
        rope_kernel<<<(npq + 255) / 256, 256, 0, stream>>>(q, fc, fs, npq, 11);
        int npk = BS * NKV * 64;
        rope_kernel<<<(npk + 255) / 256, 256, 0, stream>>>(k, fc, fs, npk, 9);
    }

    flash_kernel<<<dim3(16, NH, 2), 512, 0, stream>>>(q, k, vT, attn);

    cvt_bf16<<<2048, 256, 0, stream>>>(wo, wb, (4096 * 4096) / 8);
    gemm256<float><<<dim3(16, 16), 512, 0, stream>>>(attn, wb, out, BS, NH * HD, 4096);
}